// Round 6
// baseline (12952.371 us; speedup 1.0000x reference)
//
#include <hip/hip_runtime.h>
#include <cstddef>

// ---------------------------------------------------------------------------
// EGNN layer, fp32. R6 = R5 structure + perf fixes:
//   - edge: LDS stride 72->68, m-reduction restructured to 2-way banks
//   - node_pre / gru: wave-GEMM versions with LDS-staged weights (from R2,
//     validated in the R2 run)
//   sort chain + xout unchanged from R5 (validated).
// ---------------------------------------------------------------------------

__device__ __forceinline__ float silu_f(float v) {
    float s = 1.0f / (1.0f + expf(-v));
    return v * s;
}
__device__ __forceinline__ float sigmoid_f(float v) { return 1.0f / (1.0f + expf(-v)); }

// ---------------- sort: histogram / scan / scatter / stable fix --------------
__global__ __launch_bounds__(256) void hist_kernel(
    const int* __restrict__ src, int* __restrict__ hist, int E)
{
    int i = blockIdx.x * 256 + threadIdx.x;
    int stride = gridDim.x * 256;
    for (; i < E; i += stride) atomicAdd(&hist[src[i]], 1);
}

#define SCAN_CHUNK 2048

__global__ __launch_bounds__(256) void scanA_kernel(
    const int* __restrict__ hist, int* __restrict__ blksum, int N)
{
    __shared__ int sred[256];
    int b = blockIdx.x, tx = threadIdx.x;
    int base = b * SCAN_CHUNK + tx * 8;
    int s = 0;
    #pragma unroll
    for (int i = 0; i < 8; ++i) { int idx = base + i; if (idx < N) s += hist[idx]; }
    sred[tx] = s; __syncthreads();
    for (int off = 128; off > 0; off >>= 1) {
        if (tx < off) sred[tx] += sred[tx + off];
        __syncthreads();
    }
    if (tx == 0) blksum[b] = sred[0];
}

__global__ void scanB_kernel(int* __restrict__ blksum, int B)
{
    if (blockIdx.x == 0 && threadIdx.x == 0) {
        int acc = 0;
        for (int i = 0; i < B; ++i) { int v = blksum[i]; blksum[i] = acc; acc += v; }
    }
}

__global__ __launch_bounds__(256) void scanC_kernel(
    const int* __restrict__ hist, const int* __restrict__ blksum,
    int* __restrict__ cursor, int N)
{
    __shared__ int sscan[256];
    int b = blockIdx.x, tx = threadIdx.x;
    int base = b * SCAN_CHUNK + tx * 8;
    int s = 0;
    #pragma unroll
    for (int i = 0; i < 8; ++i) { int idx = base + i; if (idx < N) s += hist[idx]; }
    int mysum = s;
    sscan[tx] = s; __syncthreads();
    for (int off = 1; off < 256; off <<= 1) {
        int v = (tx >= off) ? sscan[tx - off] : 0;
        __syncthreads();
        sscan[tx] += v;
        __syncthreads();
    }
    int run = blksum[b] + sscan[tx] - mysum;
    #pragma unroll
    for (int i = 0; i < 8; ++i) {
        int idx = base + i;
        if (idx < N) { cursor[idx] = run; run += hist[idx]; }
    }
}

__global__ __launch_bounds__(256) void scatter_kernel(
    const int* __restrict__ src, int* __restrict__ cursor,
    int* __restrict__ order, int E)
{
    int i = blockIdx.x * 256 + threadIdx.x;
    int stride = gridDim.x * 256;
    for (; i < E; i += stride) {
        int p = atomicAdd(&cursor[src[i]], 1);
        order[p] = i;
    }
}

__global__ __launch_bounds__(256) void sortseg_kernel(
    const int* __restrict__ cursor, const int* __restrict__ hist,
    int* __restrict__ order, int N)
{
    int n = blockIdx.x * 256 + threadIdx.x;
    if (n >= N) return;
    int cnt = hist[n];
    int st = cursor[n] - cnt;
    for (int i = 1; i < cnt; ++i) {
        int v = order[st + i];
        int j = i - 1;
        while (j >= 0 && order[st + j] > v) { order[st + j + 1] = order[st + j]; --j; }
        order[st + j + 1] = v;
    }
}

// ---------------- wave-GEMM micro-kernel (16 rows x 64 outs per wave) --------
template<int WS>
__device__ __forceinline__ void wave_gemm4x4(
    const float (*__restrict__ A)[68], const float* __restrict__ WT,
    int te, int tf, float (&acc)[4][4])
{
    #pragma unroll
    for (int q = 0; q < 4; ++q)
        acc[q][0] = acc[q][1] = acc[q][2] = acc[q][3] = 0.0f;
    const float* a0 = A[4 * te + 0];
    const float* a1 = A[4 * te + 1];
    const float* a2 = A[4 * te + 2];
    const float* a3 = A[4 * te + 3];
    const float* wp = WT + 4 * tf;

    auto fma4 = [&](float x0, float x1, float x2, float x3, float4 w) {
        acc[0][0] += x0 * w.x; acc[0][1] += x0 * w.y; acc[0][2] += x0 * w.z; acc[0][3] += x0 * w.w;
        acc[1][0] += x1 * w.x; acc[1][1] += x1 * w.y; acc[1][2] += x1 * w.z; acc[1][3] += x1 * w.w;
        acc[2][0] += x2 * w.x; acc[2][1] += x2 * w.y; acc[2][2] += x2 * w.z; acc[2][3] += x2 * w.w;
        acc[3][0] += x3 * w.x; acc[3][1] += x3 * w.y; acc[3][2] += x3 * w.z; acc[3][3] += x3 * w.w;
    };

    #pragma unroll
    for (int k = 0; k < 64; k += 4) {
        float4 av0 = *(const float4*)(a0 + k);
        float4 av1 = *(const float4*)(a1 + k);
        float4 av2 = *(const float4*)(a2 + k);
        float4 av3 = *(const float4*)(a3 + k);
        float4 wv0 = *(const float4*)(wp + (size_t)(k + 0) * WS);
        float4 wv1 = *(const float4*)(wp + (size_t)(k + 1) * WS);
        float4 wv2 = *(const float4*)(wp + (size_t)(k + 2) * WS);
        float4 wv3 = *(const float4*)(wp + (size_t)(k + 3) * WS);
        fma4(av0.x, av1.x, av2.x, av3.x, wv0);
        fma4(av0.y, av1.y, av2.y, av3.y, wv1);
        fma4(av0.z, av1.z, av2.z, av3.z, wv2);
        fma4(av0.w, av1.w, av2.w, av3.w, wv3);
    }
}

// ---------------- K1: H1a / H1b (wave-GEMM, weights in LDS) ------------------
__global__ __launch_bounds__(512, 4) void node_pre_kernel(
    const float* __restrict__ h, const float* __restrict__ W1,
    const float* __restrict__ b1,
    float* __restrict__ H1a, float* __restrict__ H1b, int N)
{
    __shared__ float sWaT[64][64];   // [k][f] = W1[f][k]
    __shared__ float sWbT[64][64];   // [k][f] = W1[f][64+k]
    __shared__ float sb1[64];
    __shared__ float sT[8][16][68];

    int tx = threadIdx.x;
    for (int i = tx; i < 64 * 64; i += 512) {
        int f = i >> 6, k = i & 63;
        sWaT[k][f] = W1[f * 129 + k];
        sWbT[k][f] = W1[f * 129 + 64 + k];
    }
    if (tx < 64) sb1[tx] = b1[tx];
    __syncthreads();

    int wid = tx >> 6, lane = tx & 63;
    int te = lane >> 4, tf = lane & 15;
    int el = lane >> 2, j = lane & 3;
    float (*A)[68] = sT[wid];

    int ntile = (N + 15) >> 4;
    for (int t = blockIdx.x * 8 + wid; t < ntile; t += gridDim.x * 8) {
        int n0 = t << 4;
        int n = n0 + el;
        int nc = (n < N) ? n : (N - 1);
        const float* hp = h + (size_t)nc * 64 + j * 16;
        #pragma unroll
        for (int q = 0; q < 4; ++q)
            *(float4*)&A[el][j * 16 + 4 * q] = *(const float4*)(hp + 4 * q);

        float acc[4][4];
        wave_gemm4x4<64>(A, &sWaT[0][0], te, tf, acc);
        #pragma unroll
        for (int q = 0; q < 4; ++q) {
            int nn = n0 + 4 * te + q;
            if (nn < N) {
                float4 v;
                v.x = acc[q][0] + sb1[4 * tf + 0];
                v.y = acc[q][1] + sb1[4 * tf + 1];
                v.z = acc[q][2] + sb1[4 * tf + 2];
                v.w = acc[q][3] + sb1[4 * tf + 3];
                *(float4*)(H1a + (size_t)nn * 64 + 4 * tf) = v;
            }
        }
        wave_gemm4x4<64>(A, &sWbT[0][0], te, tf, acc);
        #pragma unroll
        for (int q = 0; q < 4; ++q) {
            int nn = n0 + 4 * te + q;
            if (nn < N) {
                float4 v = make_float4(acc[q][0], acc[q][1], acc[q][2], acc[q][3]);
                *(float4*)(H1b + (size_t)nn * 64 + 4 * tf) = v;
            }
        }
    }
}

// ---------------- K2: edge pipeline on sorted order --------------------------
__device__ __forceinline__ void tile_gemm(
    const float (*__restrict__ Ain)[68],   // [k][e]
    const float (*__restrict__ WT)[64],    // [k][f]
    int te, int tf, float (&acc)[4][4])
{
    #pragma unroll
    for (int q = 0; q < 4; ++q)
        acc[q][0] = acc[q][1] = acc[q][2] = acc[q][3] = 0.0f;
    #pragma unroll
    for (int k = 0; k < 64; k += 4) {
        float4 av[4], wv[4];
        #pragma unroll
        for (int kk = 0; kk < 4; ++kk) av[kk] = *(const float4*)&Ain[k + kk][4 * te];
        #pragma unroll
        for (int kk = 0; kk < 4; ++kk) wv[kk] = *(const float4*)&WT[k + kk][4 * tf];
        #pragma unroll
        for (int kk = 0; kk < 4; ++kk) {
            float a0 = av[kk].x, a1 = av[kk].y, a2 = av[kk].z, a3 = av[kk].w;
            float w0 = wv[kk].x, w1 = wv[kk].y, w2 = wv[kk].z, w3 = wv[kk].w;
            acc[0][0] += a0 * w0; acc[0][1] += a0 * w1; acc[0][2] += a0 * w2; acc[0][3] += a0 * w3;
            acc[1][0] += a1 * w0; acc[1][1] += a1 * w1; acc[1][2] += a1 * w2; acc[1][3] += a1 * w3;
            acc[2][0] += a2 * w0; acc[2][1] += a2 * w1; acc[2][2] += a2 * w2; acc[2][3] += a2 * w3;
            acc[3][0] += a3 * w0; acc[3][1] += a3 * w1; acc[3][2] += a3 * w2; acc[3][3] += a3 * w3;
        }
    }
}

__global__ __launch_bounds__(256, 2) void edge_kernel(
    const float* __restrict__ H1a, const float* __restrict__ H1b,
    const float* __restrict__ r_ij,
    const int* __restrict__ src, const int* __restrict__ dst,
    const int* __restrict__ order,
    const float* __restrict__ W1, const float* __restrict__ W2,
    const float* __restrict__ b2, const float* __restrict__ P1,
    const float* __restrict__ pb1, const float* __restrict__ P2,
    const float* __restrict__ pb2,
    float* __restrict__ m_sum, float* __restrict__ w_sorted, int E)
{
    __shared__ float sW2T[64][64];   // [k][f]
    __shared__ float sP1T[64][64];
    __shared__ float sA[64][68];     // [k][e]
    __shared__ float sB[64][68];     // [f][e] (= m) after GEMM1
    __shared__ int   sSrc[64];
    __shared__ int   sRunStart[65];
    __shared__ int   sNRuns, sValid;
    __shared__ float sP2[64], sb2v[64], spb1[64], sW1c[64];
    __shared__ float spb2s;

    int tx = threadIdx.x;
    for (int i = tx; i < 64 * 64; i += 256) {
        int f = i >> 6, k = i & 63;
        sW2T[k][f] = W2[f * 64 + k];
        sP1T[k][f] = P1[f * 64 + k];
    }
    if (tx < 64) {
        sP2[tx]  = P2[tx];
        sb2v[tx] = b2[tx];
        spb1[tx] = pb1[tx];
        sW1c[tx] = W1[tx * 129 + 128];
    }
    if (tx == 0) spb2s = pb2[0];
    __syncthreads();

    int tf = tx & 15, te = tx >> 4;
    int ntile = (E + 63) >> 6;
    for (int t = blockIdx.x; t < ntile; t += gridDim.x) {
        int e0 = t << 6;

        // ---- phase 0: gather via sorted order + first layer -> sA[k][e]
        {
            int le = tx >> 2, j = tx & 3;
            int ep = e0 + le;
            bool ok = ep < E;
            int eid = ok ? order[ep] : 0;
            int s = src[eid], d = dst[eid];
            float r = r_ij[eid];
            if (j == 0) sSrc[le] = ok ? s : -1;
            const float* pa = H1a + (size_t)s * 64 + j * 16;
            const float* pb = H1b + (size_t)d * 64 + j * 16;
            #pragma unroll
            for (int q = 0; q < 4; ++q) {
                float4 va = *(const float4*)(pa + 4 * q);
                float4 vb = *(const float4*)(pb + 4 * q);
                int f = j * 16 + 4 * q;
                sA[f + 0][le] = silu_f(va.x + vb.x + r * sW1c[f + 0]);
                sA[f + 1][le] = silu_f(va.y + vb.y + r * sW1c[f + 1]);
                sA[f + 2][le] = silu_f(va.z + vb.z + r * sW1c[f + 2]);
                sA[f + 3][le] = silu_f(va.w + vb.w + r * sW1c[f + 3]);
            }
        }
        __syncthreads();                        // B1: sA, sSrc ready

        // ---- run detection (wave 0; all ballots with full wave active) ----
        if (tx < 64) {
            int le = tx;
            int sv = sSrc[le];
            bool valid = sv >= 0;
            bool flag = valid && (le == 0 || sSrc[le - 1] != sv);
            unsigned long long vm = __ballot(valid);
            unsigned long long fm = __ballot(flag);
            if (flag) {
                int idx = __popcll(fm & ((1ull << le) - 1ull));
                sRunStart[idx] = le;
            }
            if (le == 0) {
                sNRuns = __popcll(fm);
                sValid = __popcll(vm);
            }
        }

        // ---- GEMM1: m = silu(t1@W2^T + b2) -> sB[f][e]
        {
            float acc[4][4];
            tile_gemm(sA, sW2T, te, tf, acc);
            #pragma unroll
            for (int c = 0; c < 4; ++c) {
                float b = sb2v[4 * tf + c];
                float4 m4;
                m4.x = silu_f(acc[0][c] + b);
                m4.y = silu_f(acc[1][c] + b);
                m4.z = silu_f(acc[2][c] + b);
                m4.w = silu_f(acc[3][c] + b);
                *(float4*)&sB[4 * tf + c][4 * te] = m4;
            }
        }
        __syncthreads();                        // B2: sB, run info ready

        // ---- GEMM2: p = silu(m@P1^T+pb1); w = p.P2 + pb2 -> w_sorted
        {
            float acc[4][4];
            tile_gemm(sB, sP1T, te, tf, acc);
            float w0 = 0.0f, w1 = 0.0f, w2 = 0.0f, w3 = 0.0f;
            #pragma unroll
            for (int c = 0; c < 4; ++c) {
                float p2 = sP2[4 * tf + c];
                float bb = spb1[4 * tf + c];
                w0 += silu_f(acc[0][c] + bb) * p2;
                w1 += silu_f(acc[1][c] + bb) * p2;
                w2 += silu_f(acc[2][c] + bb) * p2;
                w3 += silu_f(acc[3][c] + bb) * p2;
            }
            #pragma unroll
            for (int mask = 1; mask < 16; mask <<= 1) {
                w0 += __shfl_xor(w0, mask);
                w1 += __shfl_xor(w1, mask);
                w2 += __shfl_xor(w2, mask);
                w3 += __shfl_xor(w3, mask);
            }
            if (tf < 4) {
                int eloc = 4 * te + tf;
                int ep = e0 + eloc;
                if (ep < E) {
                    float w = ((tf == 0) ? w0 : (tf == 1) ? w1 : (tf == 2) ? w2 : w3) + spb2s;
                    w_sorted[ep] = w;
                }
            }
        }

        // ---- m segmented reduction, bank-conflict-free:
        //      wave sg covers features f = sg*16 + (lane&15);
        //      4 edge-slots per feature, combined via shfl_xor(16/32).
        {
            int l15 = tx & 15;
            int eslot = (tx >> 4) & 3;
            int sg = tx >> 6;
            int f = sg * 16 + l15;
            int nr = sNRuns, vc = sValid;
            for (int ridx = 0; ridx < nr; ++ridx) {
                int st = sRunStart[ridx];
                int en = (ridx + 1 < nr) ? sRunStart[ridx + 1] : vc;
                float s = 0.0f;
                for (int e = st + eslot; e < en; e += 4) s += sB[f][e];
                s += __shfl_xor(s, 16);
                s += __shfl_xor(s, 32);
                if (eslot == 0) {
                    int node = sSrc[st];
                    atomicAdd(&m_sum[(size_t)node * 64 + f], s);
                }
            }
        }
        __syncthreads();                        // Bend: before overwriting sA/sSrc
    }
}

// ---------------- K4: x outputs, np-faithful sequential accumulation ---------
__global__ __launch_bounds__(256) void xout_kernel(
    const float* __restrict__ x, const float* __restrict__ e_ij,
    const int* __restrict__ order, const int* __restrict__ cursor,
    const int* __restrict__ hist, const float* __restrict__ w_sorted,
    float* __restrict__ out_xmod, float* __restrict__ out_xdiff, int N)
{
#pragma clang fp contract(off)
    int n = blockIdx.x * 256 + threadIdx.x;
    if (n >= N) return;
    int cnt = hist[n];
    int st = cursor[n] - cnt;
    float x0 = x[(size_t)n * 3 + 0];
    float x1 = x[(size_t)n * 3 + 1];
    float x2 = x[(size_t)n * 3 + 2];
    float s0 = 0.0f, s1 = 0.0f, s2 = 0.0f;
    for (int i = 0; i < cnt; ++i) {
        int eid = order[st + i];
        float w = w_sorted[st + i];
        float t0 = e_ij[(size_t)eid * 3 + 0] * w;
        float t1 = e_ij[(size_t)eid * 3 + 1] * w;
        float t2 = e_ij[(size_t)eid * 3 + 2] * w;
        float r0 = x0 + t0;
        float r1 = x1 + t1;
        float r2 = x2 + t2;
        s0 = s0 + r0;
        s1 = s1 + r1;
        s2 = s2 + r2;
    }
    float c = (float)(cnt > 0 ? cnt : 1);
    float xp0 = s0 / c, xp1 = s1 / c, xp2 = s2 / c;
    out_xmod[(size_t)n * 3 + 0] = xp0 - floorf(xp0);
    out_xmod[(size_t)n * 3 + 1] = xp1 - floorf(xp1);
    out_xmod[(size_t)n * 3 + 2] = xp2 - floorf(xp2);
    out_xdiff[(size_t)n * 3 + 0] = xp0 - x0;
    out_xdiff[(size_t)n * 3 + 1] = xp1 - x1;
    out_xdiff[(size_t)n * 3 + 2] = xp2 - x2;
}

// ---------------- K3: GRU (wave-GEMM, weights in LDS) ------------------------
__global__ __launch_bounds__(512, 2) void gru_kernel(
    const float* __restrict__ h,
    const float* __restrict__ m_sum, const int* __restrict__ cnt,
    const float* __restrict__ W_ih, const float* __restrict__ W_hh,
    const float* __restrict__ b_ih, const float* __restrict__ b_hh,
    float* __restrict__ out_h, int N)
{
    __shared__ float sWihT[64][192];  // [k][f3] = W_ih[f3][k]
    __shared__ float sWhhT[64][192];
    __shared__ float sbih[192], sbhh[192];
    __shared__ float sT[8][16][68];

    int tx = threadIdx.x;
    for (int i = tx; i < 192 * 64; i += 512) {
        int f3 = i >> 6, k = i & 63;
        sWihT[k][f3] = W_ih[(size_t)f3 * 64 + k];
        sWhhT[k][f3] = W_hh[(size_t)f3 * 64 + k];
    }
    if (tx < 192) { sbih[tx] = b_ih[tx]; sbhh[tx] = b_hh[tx]; }
    __syncthreads();

    int wid = tx >> 6, lane = tx & 63;
    int te = lane >> 4, tf = lane & 15;
    int el = lane >> 2, j = lane & 3;
    float (*A)[68] = sT[wid];

    int ntile = (N + 15) >> 4;
    for (int t = blockIdx.x * 8 + wid; t < ntile; t += gridDim.x * 8) {
        int n0 = t << 4;

        // slab <- m_i = m_sum / cnt
        {
            int n = n0 + el;
            int nc = (n < N) ? n : (N - 1);
            float c = (float)max(cnt[nc], 1);
            float inv = 1.0f / c;
            const float* mp = m_sum + (size_t)nc * 64 + j * 16;
            #pragma unroll
            for (int q = 0; q < 4; ++q) {
                float4 v = *(const float4*)(mp + 4 * q);
                v.x *= inv; v.y *= inv; v.z *= inv; v.w *= inv;
                *(float4*)&A[el][j * 16 + 4 * q] = v;
            }
        }
        float gi0[4][4], gi1[4][4], gi2[4][4];
        wave_gemm4x4<192>(A, &sWihT[0][0] + 0,   te, tf, gi0);
        wave_gemm4x4<192>(A, &sWihT[0][0] + 64,  te, tf, gi1);
        wave_gemm4x4<192>(A, &sWihT[0][0] + 128, te, tf, gi2);

        // slab <- h  (wave-private slab; in-order DS per wave)
        {
            int n = n0 + el;
            int nc = (n < N) ? n : (N - 1);
            const float* hp = h + (size_t)nc * 64 + j * 16;
            #pragma unroll
            for (int q = 0; q < 4; ++q)
                *(float4*)&A[el][j * 16 + 4 * q] = *(const float4*)(hp + 4 * q);
        }
        float rr[4][4], zz[4][4], acch[4][4];
        wave_gemm4x4<192>(A, &sWhhT[0][0] + 0, te, tf, acch);
        #pragma unroll
        for (int q = 0; q < 4; ++q)
            #pragma unroll
            for (int c = 0; c < 4; ++c) {
                int f = 4 * tf + c;
                rr[q][c] = sigmoid_f(gi0[q][c] + sbih[f] + acch[q][c] + sbhh[f]);
            }
        wave_gemm4x4<192>(A, &sWhhT[0][0] + 64, te, tf, acch);
        #pragma unroll
        for (int q = 0; q < 4; ++q)
            #pragma unroll
            for (int c = 0; c < 4; ++c) {
                int f = 64 + 4 * tf + c;
                zz[q][c] = sigmoid_f(gi1[q][c] + sbih[f] + acch[q][c] + sbhh[f]);
            }
        wave_gemm4x4<192>(A, &sWhhT[0][0] + 128, te, tf, acch);
        #pragma unroll
        for (int q = 0; q < 4; ++q) {
            int nn = n0 + 4 * te + q;
            if (nn < N) {
                float4 hv = *(const float4*)&A[4 * te + q][4 * tf];
                float hvv[4] = {hv.x, hv.y, hv.z, hv.w};
                float ov[4];
                #pragma unroll
                for (int c = 0; c < 4; ++c) {
                    int f = 128 + 4 * tf + c;
                    float nnv = tanhf(gi2[q][c] + sbih[f] + rr[q][c] * (acch[q][c] + sbhh[f]));
                    ov[c] = (1.0f - zz[q][c]) * nnv + zz[q][c] * hvv[c];
                }
                float4 o = make_float4(ov[0], ov[1], ov[2], ov[3]);
                *(float4*)(out_h + (size_t)nn * 64 + 4 * tf) = o;
            }
        }
    }
}

// ---------------------------------------------------------------------------
extern "C" void kernel_launch(void* const* d_in, const int* in_sizes, int n_in,
                              void* d_out, int out_size, void* d_ws, size_t ws_size,
                              hipStream_t stream)
{
    const float* h    = (const float*)d_in[0];
    const float* x    = (const float*)d_in[1];
    const float* r_ij = (const float*)d_in[2];
    const float* e_ij = (const float*)d_in[3];
    const int*   src  = (const int*)d_in[4];
    const int*   dst  = (const int*)d_in[5];
    const float* W1   = (const float*)d_in[6];
    const float* b1   = (const float*)d_in[7];
    const float* W2   = (const float*)d_in[8];
    const float* b2   = (const float*)d_in[9];
    const float* P1   = (const float*)d_in[10];
    const float* pb1  = (const float*)d_in[11];
    const float* P2   = (const float*)d_in[12];
    const float* pb2  = (const float*)d_in[13];
    const float* W_ih = (const float*)d_in[14];
    const float* W_hh = (const float*)d_in[15];
    const float* b_ih = (const float*)d_in[16];
    const float* b_hh = (const float*)d_in[17];

    int N = in_sizes[0] / 64;
    int E = in_sizes[2];

    float* ws       = (float*)d_ws;
    float* H1a      = ws;                               // N*64 f
    float* H1b      = H1a + (size_t)N * 64;             // N*64 f
    float* m_sum    = H1b + (size_t)N * 64;             // N*64 f
    int*   hist     = (int*)(m_sum + (size_t)N * 64);   // N    i
    int*   cursor   = hist + N;                         // N    i
    int*   order    = cursor + N;                       // E    i
    float* w_sorted = (float*)(order + E);              // E    f
    int*   blksum   = (int*)(w_sorted + E);             // ~64  i

    hipMemsetAsync(m_sum, 0, ((size_t)N * 64 + N) * sizeof(float), stream);

    // ---- stable sort edges by src ----
    hist_kernel<<<2048, 256, 0, stream>>>(src, hist, E);
    int B = (N + SCAN_CHUNK - 1) / SCAN_CHUNK;
    scanA_kernel<<<B, 256, 0, stream>>>(hist, blksum, N);
    scanB_kernel<<<1, 64, 0, stream>>>(blksum, B);
    scanC_kernel<<<B, 256, 0, stream>>>(hist, blksum, cursor, N);
    scatter_kernel<<<2048, 256, 0, stream>>>(src, cursor, order, E);
    sortseg_kernel<<<(N + 255) / 256, 256, 0, stream>>>(cursor, hist, order, N);

    // ---- node precompute (wave-GEMM) ----
    int ntile_n = (N + 15) / 16;
    int grid_n = (ntile_n + 7) / 8;
    node_pre_kernel<<<grid_n, 512, 0, stream>>>(h, W1, b1, H1a, H1b, N);

    // ---- edge pipeline ----
    edge_kernel<<<2048, 256, 0, stream>>>(H1a, H1b, r_ij, src, dst,
        order, W1, W2, b2, P1, pb1, P2, pb2, m_sum, w_sorted, E);

    // ---- outputs ----
    float* out_xmod  = (float*)d_out;
    float* out_xdiff = out_xmod + (size_t)N * 3;
    float* out_h     = out_xdiff + (size_t)N * 3;
    xout_kernel<<<(N + 255) / 256, 256, 0, stream>>>(x, e_ij, order, cursor,
        hist, w_sorted, out_xmod, out_xdiff, N);
    gru_kernel<<<grid_n, 512, 0, stream>>>(h, m_sum, hist,
        W_ih, W_hh, b_ih, b_hh, out_h, N);
}

// Round 7
// 12577.582 us; speedup vs baseline: 1.0298x; 1.0298x over previous
//
#include <hip/hip_runtime.h>
#include <cstddef>

// ---------------------------------------------------------------------------
// EGNN layer, fp32. R7 = R6 with register-spill fix:
//   - gru_kernel:     __launch_bounds__(512,1)  (was (512,2) -> 128-VGPR cap
//                     -> ~96 live accumulator floats spilled to scratch ->
//                     14.8 GB scratch traffic, 9.4 ms). Cap now 256.
//   - node_pre_kernel:__launch_bounds__(512,2)  (was (512,4) -> 64-VGPR cap).
//   All algorithmic code identical to the passing R6 run.
// ---------------------------------------------------------------------------

__device__ __forceinline__ float silu_f(float v) {
    float s = 1.0f / (1.0f + expf(-v));
    return v * s;
}
__device__ __forceinline__ float sigmoid_f(float v) { return 1.0f / (1.0f + expf(-v)); }

// ---------------- sort: histogram / scan / scatter / stable fix --------------
__global__ __launch_bounds__(256) void hist_kernel(
    const int* __restrict__ src, int* __restrict__ hist, int E)
{
    int i = blockIdx.x * 256 + threadIdx.x;
    int stride = gridDim.x * 256;
    for (; i < E; i += stride) atomicAdd(&hist[src[i]], 1);
}

#define SCAN_CHUNK 2048

__global__ __launch_bounds__(256) void scanA_kernel(
    const int* __restrict__ hist, int* __restrict__ blksum, int N)
{
    __shared__ int sred[256];
    int b = blockIdx.x, tx = threadIdx.x;
    int base = b * SCAN_CHUNK + tx * 8;
    int s = 0;
    #pragma unroll
    for (int i = 0; i < 8; ++i) { int idx = base + i; if (idx < N) s += hist[idx]; }
    sred[tx] = s; __syncthreads();
    for (int off = 128; off > 0; off >>= 1) {
        if (tx < off) sred[tx] += sred[tx + off];
        __syncthreads();
    }
    if (tx == 0) blksum[b] = sred[0];
}

__global__ void scanB_kernel(int* __restrict__ blksum, int B)
{
    if (blockIdx.x == 0 && threadIdx.x == 0) {
        int acc = 0;
        for (int i = 0; i < B; ++i) { int v = blksum[i]; blksum[i] = acc; acc += v; }
    }
}

__global__ __launch_bounds__(256) void scanC_kernel(
    const int* __restrict__ hist, const int* __restrict__ blksum,
    int* __restrict__ cursor, int N)
{
    __shared__ int sscan[256];
    int b = blockIdx.x, tx = threadIdx.x;
    int base = b * SCAN_CHUNK + tx * 8;
    int s = 0;
    #pragma unroll
    for (int i = 0; i < 8; ++i) { int idx = base + i; if (idx < N) s += hist[idx]; }
    int mysum = s;
    sscan[tx] = s; __syncthreads();
    for (int off = 1; off < 256; off <<= 1) {
        int v = (tx >= off) ? sscan[tx - off] : 0;
        __syncthreads();
        sscan[tx] += v;
        __syncthreads();
    }
    int run = blksum[b] + sscan[tx] - mysum;
    #pragma unroll
    for (int i = 0; i < 8; ++i) {
        int idx = base + i;
        if (idx < N) { cursor[idx] = run; run += hist[idx]; }
    }
}

__global__ __launch_bounds__(256) void scatter_kernel(
    const int* __restrict__ src, int* __restrict__ cursor,
    int* __restrict__ order, int E)
{
    int i = blockIdx.x * 256 + threadIdx.x;
    int stride = gridDim.x * 256;
    for (; i < E; i += stride) {
        int p = atomicAdd(&cursor[src[i]], 1);
        order[p] = i;
    }
}

__global__ __launch_bounds__(256) void sortseg_kernel(
    const int* __restrict__ cursor, const int* __restrict__ hist,
    int* __restrict__ order, int N)
{
    int n = blockIdx.x * 256 + threadIdx.x;
    if (n >= N) return;
    int cnt = hist[n];
    int st = cursor[n] - cnt;
    for (int i = 1; i < cnt; ++i) {
        int v = order[st + i];
        int j = i - 1;
        while (j >= 0 && order[st + j] > v) { order[st + j + 1] = order[st + j]; --j; }
        order[st + j + 1] = v;
    }
}

// ---------------- wave-GEMM micro-kernel (16 rows x 64 outs per wave) --------
template<int WS>
__device__ __forceinline__ void wave_gemm4x4(
    const float (*__restrict__ A)[68], const float* __restrict__ WT,
    int te, int tf, float (&acc)[4][4])
{
    #pragma unroll
    for (int q = 0; q < 4; ++q)
        acc[q][0] = acc[q][1] = acc[q][2] = acc[q][3] = 0.0f;
    const float* a0 = A[4 * te + 0];
    const float* a1 = A[4 * te + 1];
    const float* a2 = A[4 * te + 2];
    const float* a3 = A[4 * te + 3];
    const float* wp = WT + 4 * tf;

    auto fma4 = [&](float x0, float x1, float x2, float x3, float4 w) {
        acc[0][0] += x0 * w.x; acc[0][1] += x0 * w.y; acc[0][2] += x0 * w.z; acc[0][3] += x0 * w.w;
        acc[1][0] += x1 * w.x; acc[1][1] += x1 * w.y; acc[1][2] += x1 * w.z; acc[1][3] += x1 * w.w;
        acc[2][0] += x2 * w.x; acc[2][1] += x2 * w.y; acc[2][2] += x2 * w.z; acc[2][3] += x2 * w.w;
        acc[3][0] += x3 * w.x; acc[3][1] += x3 * w.y; acc[3][2] += x3 * w.z; acc[3][3] += x3 * w.w;
    };

    #pragma unroll
    for (int k = 0; k < 64; k += 4) {
        float4 av0 = *(const float4*)(a0 + k);
        float4 av1 = *(const float4*)(a1 + k);
        float4 av2 = *(const float4*)(a2 + k);
        float4 av3 = *(const float4*)(a3 + k);
        float4 wv0 = *(const float4*)(wp + (size_t)(k + 0) * WS);
        float4 wv1 = *(const float4*)(wp + (size_t)(k + 1) * WS);
        float4 wv2 = *(const float4*)(wp + (size_t)(k + 2) * WS);
        float4 wv3 = *(const float4*)(wp + (size_t)(k + 3) * WS);
        fma4(av0.x, av1.x, av2.x, av3.x, wv0);
        fma4(av0.y, av1.y, av2.y, av3.y, wv1);
        fma4(av0.z, av1.z, av2.z, av3.z, wv2);
        fma4(av0.w, av1.w, av2.w, av3.w, wv3);
    }
}

// ---------------- K1: H1a / H1b (wave-GEMM, weights in LDS) ------------------
__global__ __launch_bounds__(512, 2) void node_pre_kernel(
    const float* __restrict__ h, const float* __restrict__ W1,
    const float* __restrict__ b1,
    float* __restrict__ H1a, float* __restrict__ H1b, int N)
{
    __shared__ float sWaT[64][64];   // [k][f] = W1[f][k]
    __shared__ float sWbT[64][64];   // [k][f] = W1[f][64+k]
    __shared__ float sb1[64];
    __shared__ float sT[8][16][68];

    int tx = threadIdx.x;
    for (int i = tx; i < 64 * 64; i += 512) {
        int f = i >> 6, k = i & 63;
        sWaT[k][f] = W1[f * 129 + k];
        sWbT[k][f] = W1[f * 129 + 64 + k];
    }
    if (tx < 64) sb1[tx] = b1[tx];
    __syncthreads();

    int wid = tx >> 6, lane = tx & 63;
    int te = lane >> 4, tf = lane & 15;
    int el = lane >> 2, j = lane & 3;
    float (*A)[68] = sT[wid];

    int ntile = (N + 15) >> 4;
    for (int t = blockIdx.x * 8 + wid; t < ntile; t += gridDim.x * 8) {
        int n0 = t << 4;
        int n = n0 + el;
        int nc = (n < N) ? n : (N - 1);
        const float* hp = h + (size_t)nc * 64 + j * 16;
        #pragma unroll
        for (int q = 0; q < 4; ++q)
            *(float4*)&A[el][j * 16 + 4 * q] = *(const float4*)(hp + 4 * q);

        float acc[4][4];
        wave_gemm4x4<64>(A, &sWaT[0][0], te, tf, acc);
        #pragma unroll
        for (int q = 0; q < 4; ++q) {
            int nn = n0 + 4 * te + q;
            if (nn < N) {
                float4 v;
                v.x = acc[q][0] + sb1[4 * tf + 0];
                v.y = acc[q][1] + sb1[4 * tf + 1];
                v.z = acc[q][2] + sb1[4 * tf + 2];
                v.w = acc[q][3] + sb1[4 * tf + 3];
                *(float4*)(H1a + (size_t)nn * 64 + 4 * tf) = v;
            }
        }
        wave_gemm4x4<64>(A, &sWbT[0][0], te, tf, acc);
        #pragma unroll
        for (int q = 0; q < 4; ++q) {
            int nn = n0 + 4 * te + q;
            if (nn < N) {
                float4 v = make_float4(acc[q][0], acc[q][1], acc[q][2], acc[q][3]);
                *(float4*)(H1b + (size_t)nn * 64 + 4 * tf) = v;
            }
        }
    }
}

// ---------------- K2: edge pipeline on sorted order --------------------------
__device__ __forceinline__ void tile_gemm(
    const float (*__restrict__ Ain)[68],   // [k][e]
    const float (*__restrict__ WT)[64],    // [k][f]
    int te, int tf, float (&acc)[4][4])
{
    #pragma unroll
    for (int q = 0; q < 4; ++q)
        acc[q][0] = acc[q][1] = acc[q][2] = acc[q][3] = 0.0f;
    #pragma unroll
    for (int k = 0; k < 64; k += 4) {
        float4 av[4], wv[4];
        #pragma unroll
        for (int kk = 0; kk < 4; ++kk) av[kk] = *(const float4*)&Ain[k + kk][4 * te];
        #pragma unroll
        for (int kk = 0; kk < 4; ++kk) wv[kk] = *(const float4*)&WT[k + kk][4 * tf];
        #pragma unroll
        for (int kk = 0; kk < 4; ++kk) {
            float a0 = av[kk].x, a1 = av[kk].y, a2 = av[kk].z, a3 = av[kk].w;
            float w0 = wv[kk].x, w1 = wv[kk].y, w2 = wv[kk].z, w3 = wv[kk].w;
            acc[0][0] += a0 * w0; acc[0][1] += a0 * w1; acc[0][2] += a0 * w2; acc[0][3] += a0 * w3;
            acc[1][0] += a1 * w0; acc[1][1] += a1 * w1; acc[1][2] += a1 * w2; acc[1][3] += a1 * w3;
            acc[2][0] += a2 * w0; acc[2][1] += a2 * w1; acc[2][2] += a2 * w2; acc[2][3] += a2 * w3;
            acc[3][0] += a3 * w0; acc[3][1] += a3 * w1; acc[3][2] += a3 * w2; acc[3][3] += a3 * w3;
        }
    }
}

__global__ __launch_bounds__(256, 2) void edge_kernel(
    const float* __restrict__ H1a, const float* __restrict__ H1b,
    const float* __restrict__ r_ij,
    const int* __restrict__ src, const int* __restrict__ dst,
    const int* __restrict__ order,
    const float* __restrict__ W1, const float* __restrict__ W2,
    const float* __restrict__ b2, const float* __restrict__ P1,
    const float* __restrict__ pb1, const float* __restrict__ P2,
    const float* __restrict__ pb2,
    float* __restrict__ m_sum, float* __restrict__ w_sorted, int E)
{
    __shared__ float sW2T[64][64];   // [k][f]
    __shared__ float sP1T[64][64];
    __shared__ float sA[64][68];     // [k][e]
    __shared__ float sB[64][68];     // [f][e] (= m) after GEMM1
    __shared__ int   sSrc[64];
    __shared__ int   sRunStart[65];
    __shared__ int   sNRuns, sValid;
    __shared__ float sP2[64], sb2v[64], spb1[64], sW1c[64];
    __shared__ float spb2s;

    int tx = threadIdx.x;
    for (int i = tx; i < 64 * 64; i += 256) {
        int f = i >> 6, k = i & 63;
        sW2T[k][f] = W2[f * 64 + k];
        sP1T[k][f] = P1[f * 64 + k];
    }
    if (tx < 64) {
        sP2[tx]  = P2[tx];
        sb2v[tx] = b2[tx];
        spb1[tx] = pb1[tx];
        sW1c[tx] = W1[tx * 129 + 128];
    }
    if (tx == 0) spb2s = pb2[0];
    __syncthreads();

    int tf = tx & 15, te = tx >> 4;
    int ntile = (E + 63) >> 6;
    for (int t = blockIdx.x; t < ntile; t += gridDim.x) {
        int e0 = t << 6;

        // ---- phase 0: gather via sorted order + first layer -> sA[k][e]
        {
            int le = tx >> 2, j = tx & 3;
            int ep = e0 + le;
            bool ok = ep < E;
            int eid = ok ? order[ep] : 0;
            int s = src[eid], d = dst[eid];
            float r = r_ij[eid];
            if (j == 0) sSrc[le] = ok ? s : -1;
            const float* pa = H1a + (size_t)s * 64 + j * 16;
            const float* pb = H1b + (size_t)d * 64 + j * 16;
            #pragma unroll
            for (int q = 0; q < 4; ++q) {
                float4 va = *(const float4*)(pa + 4 * q);
                float4 vb = *(const float4*)(pb + 4 * q);
                int f = j * 16 + 4 * q;
                sA[f + 0][le] = silu_f(va.x + vb.x + r * sW1c[f + 0]);
                sA[f + 1][le] = silu_f(va.y + vb.y + r * sW1c[f + 1]);
                sA[f + 2][le] = silu_f(va.z + vb.z + r * sW1c[f + 2]);
                sA[f + 3][le] = silu_f(va.w + vb.w + r * sW1c[f + 3]);
            }
        }
        __syncthreads();                        // B1: sA, sSrc ready

        // ---- run detection (wave 0; all ballots with full wave active) ----
        if (tx < 64) {
            int le = tx;
            int sv = sSrc[le];
            bool valid = sv >= 0;
            bool flag = valid && (le == 0 || sSrc[le - 1] != sv);
            unsigned long long vm = __ballot(valid);
            unsigned long long fm = __ballot(flag);
            if (flag) {
                int idx = __popcll(fm & ((1ull << le) - 1ull));
                sRunStart[idx] = le;
            }
            if (le == 0) {
                sNRuns = __popcll(fm);
                sValid = __popcll(vm);
            }
        }

        // ---- GEMM1: m = silu(t1@W2^T + b2) -> sB[f][e]
        {
            float acc[4][4];
            tile_gemm(sA, sW2T, te, tf, acc);
            #pragma unroll
            for (int c = 0; c < 4; ++c) {
                float b = sb2v[4 * tf + c];
                float4 m4;
                m4.x = silu_f(acc[0][c] + b);
                m4.y = silu_f(acc[1][c] + b);
                m4.z = silu_f(acc[2][c] + b);
                m4.w = silu_f(acc[3][c] + b);
                *(float4*)&sB[4 * tf + c][4 * te] = m4;
            }
        }
        __syncthreads();                        // B2: sB, run info ready

        // ---- GEMM2: p = silu(m@P1^T+pb1); w = p.P2 + pb2 -> w_sorted
        {
            float acc[4][4];
            tile_gemm(sB, sP1T, te, tf, acc);
            float w0 = 0.0f, w1 = 0.0f, w2 = 0.0f, w3 = 0.0f;
            #pragma unroll
            for (int c = 0; c < 4; ++c) {
                float p2 = sP2[4 * tf + c];
                float bb = spb1[4 * tf + c];
                w0 += silu_f(acc[0][c] + bb) * p2;
                w1 += silu_f(acc[1][c] + bb) * p2;
                w2 += silu_f(acc[2][c] + bb) * p2;
                w3 += silu_f(acc[3][c] + bb) * p2;
            }
            #pragma unroll
            for (int mask = 1; mask < 16; mask <<= 1) {
                w0 += __shfl_xor(w0, mask);
                w1 += __shfl_xor(w1, mask);
                w2 += __shfl_xor(w2, mask);
                w3 += __shfl_xor(w3, mask);
            }
            if (tf < 4) {
                int eloc = 4 * te + tf;
                int ep = e0 + eloc;
                if (ep < E) {
                    float w = ((tf == 0) ? w0 : (tf == 1) ? w1 : (tf == 2) ? w2 : w3) + spb2s;
                    w_sorted[ep] = w;
                }
            }
        }

        // ---- m segmented reduction, bank-conflict-free layout
        {
            int l15 = tx & 15;
            int eslot = (tx >> 4) & 3;
            int sg = tx >> 6;
            int f = sg * 16 + l15;
            int nr = sNRuns, vc = sValid;
            for (int ridx = 0; ridx < nr; ++ridx) {
                int st = sRunStart[ridx];
                int en = (ridx + 1 < nr) ? sRunStart[ridx + 1] : vc;
                float s = 0.0f;
                for (int e = st + eslot; e < en; e += 4) s += sB[f][e];
                s += __shfl_xor(s, 16);
                s += __shfl_xor(s, 32);
                if (eslot == 0) {
                    int node = sSrc[st];
                    atomicAdd(&m_sum[(size_t)node * 64 + f], s);
                }
            }
        }
        __syncthreads();                        // Bend: before overwriting sA/sSrc
    }
}

// ---------------- K4: x outputs, np-faithful sequential accumulation ---------
__global__ __launch_bounds__(256) void xout_kernel(
    const float* __restrict__ x, const float* __restrict__ e_ij,
    const int* __restrict__ order, const int* __restrict__ cursor,
    const int* __restrict__ hist, const float* __restrict__ w_sorted,
    float* __restrict__ out_xmod, float* __restrict__ out_xdiff, int N)
{
#pragma clang fp contract(off)
    int n = blockIdx.x * 256 + threadIdx.x;
    if (n >= N) return;
    int cnt = hist[n];
    int st = cursor[n] - cnt;
    float x0 = x[(size_t)n * 3 + 0];
    float x1 = x[(size_t)n * 3 + 1];
    float x2 = x[(size_t)n * 3 + 2];
    float s0 = 0.0f, s1 = 0.0f, s2 = 0.0f;
    for (int i = 0; i < cnt; ++i) {
        int eid = order[st + i];
        float w = w_sorted[st + i];
        float t0 = e_ij[(size_t)eid * 3 + 0] * w;
        float t1 = e_ij[(size_t)eid * 3 + 1] * w;
        float t2 = e_ij[(size_t)eid * 3 + 2] * w;
        float r0 = x0 + t0;
        float r1 = x1 + t1;
        float r2 = x2 + t2;
        s0 = s0 + r0;
        s1 = s1 + r1;
        s2 = s2 + r2;
    }
    float c = (float)(cnt > 0 ? cnt : 1);
    float xp0 = s0 / c, xp1 = s1 / c, xp2 = s2 / c;
    out_xmod[(size_t)n * 3 + 0] = xp0 - floorf(xp0);
    out_xmod[(size_t)n * 3 + 1] = xp1 - floorf(xp1);
    out_xmod[(size_t)n * 3 + 2] = xp2 - floorf(xp2);
    out_xdiff[(size_t)n * 3 + 0] = xp0 - x0;
    out_xdiff[(size_t)n * 3 + 1] = xp1 - x1;
    out_xdiff[(size_t)n * 3 + 2] = xp2 - x2;
}

// ---------------- K3: GRU (wave-GEMM, weights in LDS) ------------------------
__global__ __launch_bounds__(512, 1) void gru_kernel(
    const float* __restrict__ h,
    const float* __restrict__ m_sum, const int* __restrict__ cnt,
    const float* __restrict__ W_ih, const float* __restrict__ W_hh,
    const float* __restrict__ b_ih, const float* __restrict__ b_hh,
    float* __restrict__ out_h, int N)
{
    __shared__ float sWihT[64][192];  // [k][f3] = W_ih[f3][k]
    __shared__ float sWhhT[64][192];
    __shared__ float sbih[192], sbhh[192];
    __shared__ float sT[8][16][68];

    int tx = threadIdx.x;
    for (int i = tx; i < 192 * 64; i += 512) {
        int f3 = i >> 6, k = i & 63;
        sWihT[k][f3] = W_ih[(size_t)f3 * 64 + k];
        sWhhT[k][f3] = W_hh[(size_t)f3 * 64 + k];
    }
    if (tx < 192) { sbih[tx] = b_ih[tx]; sbhh[tx] = b_hh[tx]; }
    __syncthreads();

    int wid = tx >> 6, lane = tx & 63;
    int te = lane >> 4, tf = lane & 15;
    int el = lane >> 2, j = lane & 3;
    float (*A)[68] = sT[wid];

    int ntile = (N + 15) >> 4;
    for (int t = blockIdx.x * 8 + wid; t < ntile; t += gridDim.x * 8) {
        int n0 = t << 4;

        // slab <- m_i = m_sum / cnt
        {
            int n = n0 + el;
            int nc = (n < N) ? n : (N - 1);
            float c = (float)max(cnt[nc], 1);
            float inv = 1.0f / c;
            const float* mp = m_sum + (size_t)nc * 64 + j * 16;
            #pragma unroll
            for (int q = 0; q < 4; ++q) {
                float4 v = *(const float4*)(mp + 4 * q);
                v.x *= inv; v.y *= inv; v.z *= inv; v.w *= inv;
                *(float4*)&A[el][j * 16 + 4 * q] = v;
            }
        }
        float gi0[4][4], gi1[4][4], gi2[4][4];
        wave_gemm4x4<192>(A, &sWihT[0][0] + 0,   te, tf, gi0);
        wave_gemm4x4<192>(A, &sWihT[0][0] + 64,  te, tf, gi1);
        wave_gemm4x4<192>(A, &sWihT[0][0] + 128, te, tf, gi2);

        // slab <- h  (wave-private slab; in-order DS per wave)
        {
            int n = n0 + el;
            int nc = (n < N) ? n : (N - 1);
            const float* hp = h + (size_t)nc * 64 + j * 16;
            #pragma unroll
            for (int q = 0; q < 4; ++q)
                *(float4*)&A[el][j * 16 + 4 * q] = *(const float4*)(hp + 4 * q);
        }
        float rr[4][4], zz[4][4], acch[4][4];
        wave_gemm4x4<192>(A, &sWhhT[0][0] + 0, te, tf, acch);
        #pragma unroll
        for (int q = 0; q < 4; ++q)
            #pragma unroll
            for (int c = 0; c < 4; ++c) {
                int f = 4 * tf + c;
                rr[q][c] = sigmoid_f(gi0[q][c] + sbih[f] + acch[q][c] + sbhh[f]);
            }
        wave_gemm4x4<192>(A, &sWhhT[0][0] + 64, te, tf, acch);
        #pragma unroll
        for (int q = 0; q < 4; ++q)
            #pragma unroll
            for (int c = 0; c < 4; ++c) {
                int f = 64 + 4 * tf + c;
                zz[q][c] = sigmoid_f(gi1[q][c] + sbih[f] + acch[q][c] + sbhh[f]);
            }
        wave_gemm4x4<192>(A, &sWhhT[0][0] + 128, te, tf, acch);
        #pragma unroll
        for (int q = 0; q < 4; ++q) {
            int nn = n0 + 4 * te + q;
            if (nn < N) {
                float4 hv = *(const float4*)&A[4 * te + q][4 * tf];
                float hvv[4] = {hv.x, hv.y, hv.z, hv.w};
                float ov[4];
                #pragma unroll
                for (int c = 0; c < 4; ++c) {
                    int f = 128 + 4 * tf + c;
                    float nnv = tanhf(gi2[q][c] + sbih[f] + rr[q][c] * (acch[q][c] + sbhh[f]));
                    ov[c] = (1.0f - zz[q][c]) * nnv + zz[q][c] * hvv[c];
                }
                float4 o = make_float4(ov[0], ov[1], ov[2], ov[3]);
                *(float4*)(out_h + (size_t)nn * 64 + 4 * tf) = o;
            }
        }
    }
}

// ---------------------------------------------------------------------------
extern "C" void kernel_launch(void* const* d_in, const int* in_sizes, int n_in,
                              void* d_out, int out_size, void* d_ws, size_t ws_size,
                              hipStream_t stream)
{
    const float* h    = (const float*)d_in[0];
    const float* x    = (const float*)d_in[1];
    const float* r_ij = (const float*)d_in[2];
    const float* e_ij = (const float*)d_in[3];
    const int*   src  = (const int*)d_in[4];
    const int*   dst  = (const int*)d_in[5];
    const float* W1   = (const float*)d_in[6];
    const float* b1   = (const float*)d_in[7];
    const float* W2   = (const float*)d_in[8];
    const float* b2   = (const float*)d_in[9];
    const float* P1   = (const float*)d_in[10];
    const float* pb1  = (const float*)d_in[11];
    const float* P2   = (const float*)d_in[12];
    const float* pb2  = (const float*)d_in[13];
    const float* W_ih = (const float*)d_in[14];
    const float* W_hh = (const float*)d_in[15];
    const float* b_ih = (const float*)d_in[16];
    const float* b_hh = (const float*)d_in[17];

    int N = in_sizes[0] / 64;
    int E = in_sizes[2];

    float* ws       = (float*)d_ws;
    float* H1a      = ws;                               // N*64 f
    float* H1b      = H1a + (size_t)N * 64;             // N*64 f
    float* m_sum    = H1b + (size_t)N * 64;             // N*64 f
    int*   hist     = (int*)(m_sum + (size_t)N * 64);   // N    i
    int*   cursor   = hist + N;                         // N    i
    int*   order    = cursor + N;                       // E    i
    float* w_sorted = (float*)(order + E);              // E    f
    int*   blksum   = (int*)(w_sorted + E);             // ~64  i

    hipMemsetAsync(m_sum, 0, ((size_t)N * 64 + N) * sizeof(float), stream);

    // ---- stable sort edges by src ----
    hist_kernel<<<2048, 256, 0, stream>>>(src, hist, E);
    int B = (N + SCAN_CHUNK - 1) / SCAN_CHUNK;
    scanA_kernel<<<B, 256, 0, stream>>>(hist, blksum, N);
    scanB_kernel<<<1, 64, 0, stream>>>(blksum, B);
    scanC_kernel<<<B, 256, 0, stream>>>(hist, blksum, cursor, N);
    scatter_kernel<<<2048, 256, 0, stream>>>(src, cursor, order, E);
    sortseg_kernel<<<(N + 255) / 256, 256, 0, stream>>>(cursor, hist, order, N);

    // ---- node precompute (wave-GEMM) ----
    int ntile_n = (N + 15) / 16;
    int grid_n = (ntile_n + 7) / 8;
    node_pre_kernel<<<grid_n, 512, 0, stream>>>(h, W1, b1, H1a, H1b, N);

    // ---- edge pipeline ----
    edge_kernel<<<2048, 256, 0, stream>>>(H1a, H1b, r_ij, src, dst,
        order, W1, W2, b2, P1, pb1, P2, pb2, m_sum, w_sorted, E);

    // ---- outputs ----
    float* out_xmod  = (float*)d_out;
    float* out_xdiff = out_xmod + (size_t)N * 3;
    float* out_h     = out_xdiff + (size_t)N * 3;
    xout_kernel<<<(N + 255) / 256, 256, 0, stream>>>(x, e_ij, order, cursor,
        hist, w_sorted, out_xmod, out_xdiff, N);
    gru_kernel<<<grid_n, 512, 0, stream>>>(h, m_sum, hist,
        W_ih, W_hh, b_ih, b_hh, out_h, N);
}

// Round 8
// 4252.478 us; speedup vs baseline: 3.0458x; 2.9577x over previous
//
#include <hip/hip_runtime.h>
#include <cstddef>

// ---------------------------------------------------------------------------
// EGNN layer, fp32. R8 = R7 with gru_kernel reverted to the R5-validated
// 256-thread low-register version (the 512-thread 8-slab GRU spills ~96
// accumulator floats at the compiler's self-chosen 128-VGPR budget ->
// 14.8 GB scratch traffic, 9.4 ms; launch_bounds could not change it).
//   sort chain, node_pre (wave-GEMM), edge, xout identical to R7 (validated).
// ---------------------------------------------------------------------------

__device__ __forceinline__ float silu_f(float v) {
    float s = 1.0f / (1.0f + expf(-v));
    return v * s;
}
__device__ __forceinline__ float sigmoid_f(float v) { return 1.0f / (1.0f + expf(-v)); }

// ---------------- sort: histogram / scan / scatter / stable fix --------------
__global__ __launch_bounds__(256) void hist_kernel(
    const int* __restrict__ src, int* __restrict__ hist, int E)
{
    int i = blockIdx.x * 256 + threadIdx.x;
    int stride = gridDim.x * 256;
    for (; i < E; i += stride) atomicAdd(&hist[src[i]], 1);
}

#define SCAN_CHUNK 2048

__global__ __launch_bounds__(256) void scanA_kernel(
    const int* __restrict__ hist, int* __restrict__ blksum, int N)
{
    __shared__ int sred[256];
    int b = blockIdx.x, tx = threadIdx.x;
    int base = b * SCAN_CHUNK + tx * 8;
    int s = 0;
    #pragma unroll
    for (int i = 0; i < 8; ++i) { int idx = base + i; if (idx < N) s += hist[idx]; }
    sred[tx] = s; __syncthreads();
    for (int off = 128; off > 0; off >>= 1) {
        if (tx < off) sred[tx] += sred[tx + off];
        __syncthreads();
    }
    if (tx == 0) blksum[b] = sred[0];
}

__global__ void scanB_kernel(int* __restrict__ blksum, int B)
{
    if (blockIdx.x == 0 && threadIdx.x == 0) {
        int acc = 0;
        for (int i = 0; i < B; ++i) { int v = blksum[i]; blksum[i] = acc; acc += v; }
    }
}

__global__ __launch_bounds__(256) void scanC_kernel(
    const int* __restrict__ hist, const int* __restrict__ blksum,
    int* __restrict__ cursor, int N)
{
    __shared__ int sscan[256];
    int b = blockIdx.x, tx = threadIdx.x;
    int base = b * SCAN_CHUNK + tx * 8;
    int s = 0;
    #pragma unroll
    for (int i = 0; i < 8; ++i) { int idx = base + i; if (idx < N) s += hist[idx]; }
    int mysum = s;
    sscan[tx] = s; __syncthreads();
    for (int off = 1; off < 256; off <<= 1) {
        int v = (tx >= off) ? sscan[tx - off] : 0;
        __syncthreads();
        sscan[tx] += v;
        __syncthreads();
    }
    int run = blksum[b] + sscan[tx] - mysum;
    #pragma unroll
    for (int i = 0; i < 8; ++i) {
        int idx = base + i;
        if (idx < N) { cursor[idx] = run; run += hist[idx]; }
    }
}

__global__ __launch_bounds__(256) void scatter_kernel(
    const int* __restrict__ src, int* __restrict__ cursor,
    int* __restrict__ order, int E)
{
    int i = blockIdx.x * 256 + threadIdx.x;
    int stride = gridDim.x * 256;
    for (; i < E; i += stride) {
        int p = atomicAdd(&cursor[src[i]], 1);
        order[p] = i;
    }
}

__global__ __launch_bounds__(256) void sortseg_kernel(
    const int* __restrict__ cursor, const int* __restrict__ hist,
    int* __restrict__ order, int N)
{
    int n = blockIdx.x * 256 + threadIdx.x;
    if (n >= N) return;
    int cnt = hist[n];
    int st = cursor[n] - cnt;
    for (int i = 1; i < cnt; ++i) {
        int v = order[st + i];
        int j = i - 1;
        while (j >= 0 && order[st + j] > v) { order[st + j + 1] = order[st + j]; --j; }
        order[st + j + 1] = v;
    }
}

// ---------------- wave-GEMM micro-kernel (16 rows x 64 outs per wave) --------
template<int WS>
__device__ __forceinline__ void wave_gemm4x4(
    const float (*__restrict__ A)[68], const float* __restrict__ WT,
    int te, int tf, float (&acc)[4][4])
{
    #pragma unroll
    for (int q = 0; q < 4; ++q)
        acc[q][0] = acc[q][1] = acc[q][2] = acc[q][3] = 0.0f;
    const float* a0 = A[4 * te + 0];
    const float* a1 = A[4 * te + 1];
    const float* a2 = A[4 * te + 2];
    const float* a3 = A[4 * te + 3];
    const float* wp = WT + 4 * tf;

    auto fma4 = [&](float x0, float x1, float x2, float x3, float4 w) {
        acc[0][0] += x0 * w.x; acc[0][1] += x0 * w.y; acc[0][2] += x0 * w.z; acc[0][3] += x0 * w.w;
        acc[1][0] += x1 * w.x; acc[1][1] += x1 * w.y; acc[1][2] += x1 * w.z; acc[1][3] += x1 * w.w;
        acc[2][0] += x2 * w.x; acc[2][1] += x2 * w.y; acc[2][2] += x2 * w.z; acc[2][3] += x2 * w.w;
        acc[3][0] += x3 * w.x; acc[3][1] += x3 * w.y; acc[3][2] += x3 * w.z; acc[3][3] += x3 * w.w;
    };

    #pragma unroll
    for (int k = 0; k < 64; k += 4) {
        float4 av0 = *(const float4*)(a0 + k);
        float4 av1 = *(const float4*)(a1 + k);
        float4 av2 = *(const float4*)(a2 + k);
        float4 av3 = *(const float4*)(a3 + k);
        float4 wv0 = *(const float4*)(wp + (size_t)(k + 0) * WS);
        float4 wv1 = *(const float4*)(wp + (size_t)(k + 1) * WS);
        float4 wv2 = *(const float4*)(wp + (size_t)(k + 2) * WS);
        float4 wv3 = *(const float4*)(wp + (size_t)(k + 3) * WS);
        fma4(av0.x, av1.x, av2.x, av3.x, wv0);
        fma4(av0.y, av1.y, av2.y, av3.y, wv1);
        fma4(av0.z, av1.z, av2.z, av3.z, wv2);
        fma4(av0.w, av1.w, av2.w, av3.w, wv3);
    }
}

// ---------------- K1: H1a / H1b (wave-GEMM, weights in LDS) ------------------
__global__ __launch_bounds__(512, 2) void node_pre_kernel(
    const float* __restrict__ h, const float* __restrict__ W1,
    const float* __restrict__ b1,
    float* __restrict__ H1a, float* __restrict__ H1b, int N)
{
    __shared__ float sWaT[64][64];   // [k][f] = W1[f][k]
    __shared__ float sWbT[64][64];   // [k][f] = W1[f][64+k]
    __shared__ float sb1[64];
    __shared__ float sT[8][16][68];

    int tx = threadIdx.x;
    for (int i = tx; i < 64 * 64; i += 512) {
        int f = i >> 6, k = i & 63;
        sWaT[k][f] = W1[f * 129 + k];
        sWbT[k][f] = W1[f * 129 + 64 + k];
    }
    if (tx < 64) sb1[tx] = b1[tx];
    __syncthreads();

    int wid = tx >> 6, lane = tx & 63;
    int te = lane >> 4, tf = lane & 15;
    int el = lane >> 2, j = lane & 3;
    float (*A)[68] = sT[wid];

    int ntile = (N + 15) >> 4;
    for (int t = blockIdx.x * 8 + wid; t < ntile; t += gridDim.x * 8) {
        int n0 = t << 4;
        int n = n0 + el;
        int nc = (n < N) ? n : (N - 1);
        const float* hp = h + (size_t)nc * 64 + j * 16;
        #pragma unroll
        for (int q = 0; q < 4; ++q)
            *(float4*)&A[el][j * 16 + 4 * q] = *(const float4*)(hp + 4 * q);

        float acc[4][4];
        wave_gemm4x4<64>(A, &sWaT[0][0], te, tf, acc);
        #pragma unroll
        for (int q = 0; q < 4; ++q) {
            int nn = n0 + 4 * te + q;
            if (nn < N) {
                float4 v;
                v.x = acc[q][0] + sb1[4 * tf + 0];
                v.y = acc[q][1] + sb1[4 * tf + 1];
                v.z = acc[q][2] + sb1[4 * tf + 2];
                v.w = acc[q][3] + sb1[4 * tf + 3];
                *(float4*)(H1a + (size_t)nn * 64 + 4 * tf) = v;
            }
        }
        wave_gemm4x4<64>(A, &sWbT[0][0], te, tf, acc);
        #pragma unroll
        for (int q = 0; q < 4; ++q) {
            int nn = n0 + 4 * te + q;
            if (nn < N) {
                float4 v = make_float4(acc[q][0], acc[q][1], acc[q][2], acc[q][3]);
                *(float4*)(H1b + (size_t)nn * 64 + 4 * tf) = v;
            }
        }
    }
}

// ---------------- K2: edge pipeline on sorted order --------------------------
__device__ __forceinline__ void tile_gemm(
    const float (*__restrict__ Ain)[68],   // [k][e]
    const float (*__restrict__ WT)[64],    // [k][f]
    int te, int tf, float (&acc)[4][4])
{
    #pragma unroll
    for (int q = 0; q < 4; ++q)
        acc[q][0] = acc[q][1] = acc[q][2] = acc[q][3] = 0.0f;
    #pragma unroll
    for (int k = 0; k < 64; k += 4) {
        float4 av[4], wv[4];
        #pragma unroll
        for (int kk = 0; kk < 4; ++kk) av[kk] = *(const float4*)&Ain[k + kk][4 * te];
        #pragma unroll
        for (int kk = 0; kk < 4; ++kk) wv[kk] = *(const float4*)&WT[k + kk][4 * tf];
        #pragma unroll
        for (int kk = 0; kk < 4; ++kk) {
            float a0 = av[kk].x, a1 = av[kk].y, a2 = av[kk].z, a3 = av[kk].w;
            float w0 = wv[kk].x, w1 = wv[kk].y, w2 = wv[kk].z, w3 = wv[kk].w;
            acc[0][0] += a0 * w0; acc[0][1] += a0 * w1; acc[0][2] += a0 * w2; acc[0][3] += a0 * w3;
            acc[1][0] += a1 * w0; acc[1][1] += a1 * w1; acc[1][2] += a1 * w2; acc[1][3] += a1 * w3;
            acc[2][0] += a2 * w0; acc[2][1] += a2 * w1; acc[2][2] += a2 * w2; acc[2][3] += a2 * w3;
            acc[3][0] += a3 * w0; acc[3][1] += a3 * w1; acc[3][2] += a3 * w2; acc[3][3] += a3 * w3;
        }
    }
}

__global__ __launch_bounds__(256, 2) void edge_kernel(
    const float* __restrict__ H1a, const float* __restrict__ H1b,
    const float* __restrict__ r_ij,
    const int* __restrict__ src, const int* __restrict__ dst,
    const int* __restrict__ order,
    const float* __restrict__ W1, const float* __restrict__ W2,
    const float* __restrict__ b2, const float* __restrict__ P1,
    const float* __restrict__ pb1, const float* __restrict__ P2,
    const float* __restrict__ pb2,
    float* __restrict__ m_sum, float* __restrict__ w_sorted, int E)
{
    __shared__ float sW2T[64][64];   // [k][f]
    __shared__ float sP1T[64][64];
    __shared__ float sA[64][68];     // [k][e]
    __shared__ float sB[64][68];     // [f][e] (= m) after GEMM1
    __shared__ int   sSrc[64];
    __shared__ int   sRunStart[65];
    __shared__ int   sNRuns, sValid;
    __shared__ float sP2[64], sb2v[64], spb1[64], sW1c[64];
    __shared__ float spb2s;

    int tx = threadIdx.x;
    for (int i = tx; i < 64 * 64; i += 256) {
        int f = i >> 6, k = i & 63;
        sW2T[k][f] = W2[f * 64 + k];
        sP1T[k][f] = P1[f * 64 + k];
    }
    if (tx < 64) {
        sP2[tx]  = P2[tx];
        sb2v[tx] = b2[tx];
        spb1[tx] = pb1[tx];
        sW1c[tx] = W1[tx * 129 + 128];
    }
    if (tx == 0) spb2s = pb2[0];
    __syncthreads();

    int tf = tx & 15, te = tx >> 4;
    int ntile = (E + 63) >> 6;
    for (int t = blockIdx.x; t < ntile; t += gridDim.x) {
        int e0 = t << 6;

        // ---- phase 0: gather via sorted order + first layer -> sA[k][e]
        {
            int le = tx >> 2, j = tx & 3;
            int ep = e0 + le;
            bool ok = ep < E;
            int eid = ok ? order[ep] : 0;
            int s = src[eid], d = dst[eid];
            float r = r_ij[eid];
            if (j == 0) sSrc[le] = ok ? s : -1;
            const float* pa = H1a + (size_t)s * 64 + j * 16;
            const float* pb = H1b + (size_t)d * 64 + j * 16;
            #pragma unroll
            for (int q = 0; q < 4; ++q) {
                float4 va = *(const float4*)(pa + 4 * q);
                float4 vb = *(const float4*)(pb + 4 * q);
                int f = j * 16 + 4 * q;
                sA[f + 0][le] = silu_f(va.x + vb.x + r * sW1c[f + 0]);
                sA[f + 1][le] = silu_f(va.y + vb.y + r * sW1c[f + 1]);
                sA[f + 2][le] = silu_f(va.z + vb.z + r * sW1c[f + 2]);
                sA[f + 3][le] = silu_f(va.w + vb.w + r * sW1c[f + 3]);
            }
        }
        __syncthreads();                        // B1: sA, sSrc ready

        // ---- run detection (wave 0; all ballots with full wave active) ----
        if (tx < 64) {
            int le = tx;
            int sv = sSrc[le];
            bool valid = sv >= 0;
            bool flag = valid && (le == 0 || sSrc[le - 1] != sv);
            unsigned long long vm = __ballot(valid);
            unsigned long long fm = __ballot(flag);
            if (flag) {
                int idx = __popcll(fm & ((1ull << le) - 1ull));
                sRunStart[idx] = le;
            }
            if (le == 0) {
                sNRuns = __popcll(fm);
                sValid = __popcll(vm);
            }
        }

        // ---- GEMM1: m = silu(t1@W2^T + b2) -> sB[f][e]
        {
            float acc[4][4];
            tile_gemm(sA, sW2T, te, tf, acc);
            #pragma unroll
            for (int c = 0; c < 4; ++c) {
                float b = sb2v[4 * tf + c];
                float4 m4;
                m4.x = silu_f(acc[0][c] + b);
                m4.y = silu_f(acc[1][c] + b);
                m4.z = silu_f(acc[2][c] + b);
                m4.w = silu_f(acc[3][c] + b);
                *(float4*)&sB[4 * tf + c][4 * te] = m4;
            }
        }
        __syncthreads();                        // B2: sB, run info ready

        // ---- GEMM2: p = silu(m@P1^T+pb1); w = p.P2 + pb2 -> w_sorted
        {
            float acc[4][4];
            tile_gemm(sB, sP1T, te, tf, acc);
            float w0 = 0.0f, w1 = 0.0f, w2 = 0.0f, w3 = 0.0f;
            #pragma unroll
            for (int c = 0; c < 4; ++c) {
                float p2 = sP2[4 * tf + c];
                float bb = spb1[4 * tf + c];
                w0 += silu_f(acc[0][c] + bb) * p2;
                w1 += silu_f(acc[1][c] + bb) * p2;
                w2 += silu_f(acc[2][c] + bb) * p2;
                w3 += silu_f(acc[3][c] + bb) * p2;
            }
            #pragma unroll
            for (int mask = 1; mask < 16; mask <<= 1) {
                w0 += __shfl_xor(w0, mask);
                w1 += __shfl_xor(w1, mask);
                w2 += __shfl_xor(w2, mask);
                w3 += __shfl_xor(w3, mask);
            }
            if (tf < 4) {
                int eloc = 4 * te + tf;
                int ep = e0 + eloc;
                if (ep < E) {
                    float w = ((tf == 0) ? w0 : (tf == 1) ? w1 : (tf == 2) ? w2 : w3) + spb2s;
                    w_sorted[ep] = w;
                }
            }
        }

        // ---- m segmented reduction, bank-conflict-free layout
        {
            int l15 = tx & 15;
            int eslot = (tx >> 4) & 3;
            int sg = tx >> 6;
            int f = sg * 16 + l15;
            int nr = sNRuns, vc = sValid;
            for (int ridx = 0; ridx < nr; ++ridx) {
                int st = sRunStart[ridx];
                int en = (ridx + 1 < nr) ? sRunStart[ridx + 1] : vc;
                float s = 0.0f;
                for (int e = st + eslot; e < en; e += 4) s += sB[f][e];
                s += __shfl_xor(s, 16);
                s += __shfl_xor(s, 32);
                if (eslot == 0) {
                    int node = sSrc[st];
                    atomicAdd(&m_sum[(size_t)node * 64 + f], s);
                }
            }
        }
        __syncthreads();                        // Bend: before overwriting sA/sSrc
    }
}

// ---------------- K4: x outputs, np-faithful sequential accumulation ---------
__global__ __launch_bounds__(256) void xout_kernel(
    const float* __restrict__ x, const float* __restrict__ e_ij,
    const int* __restrict__ order, const int* __restrict__ cursor,
    const int* __restrict__ hist, const float* __restrict__ w_sorted,
    float* __restrict__ out_xmod, float* __restrict__ out_xdiff, int N)
{
#pragma clang fp contract(off)
    int n = blockIdx.x * 256 + threadIdx.x;
    if (n >= N) return;
    int cnt = hist[n];
    int st = cursor[n] - cnt;
    float x0 = x[(size_t)n * 3 + 0];
    float x1 = x[(size_t)n * 3 + 1];
    float x2 = x[(size_t)n * 3 + 2];
    float s0 = 0.0f, s1 = 0.0f, s2 = 0.0f;
    for (int i = 0; i < cnt; ++i) {
        int eid = order[st + i];
        float w = w_sorted[st + i];
        float t0 = e_ij[(size_t)eid * 3 + 0] * w;
        float t1 = e_ij[(size_t)eid * 3 + 1] * w;
        float t2 = e_ij[(size_t)eid * 3 + 2] * w;
        float r0 = x0 + t0;
        float r1 = x1 + t1;
        float r2 = x2 + t2;
        s0 = s0 + r0;
        s1 = s1 + r1;
        s2 = s2 + r2;
    }
    float c = (float)(cnt > 0 ? cnt : 1);
    float xp0 = s0 / c, xp1 = s1 / c, xp2 = s2 / c;
    out_xmod[(size_t)n * 3 + 0] = xp0 - floorf(xp0);
    out_xmod[(size_t)n * 3 + 1] = xp1 - floorf(xp1);
    out_xmod[(size_t)n * 3 + 2] = xp2 - floorf(xp2);
    out_xdiff[(size_t)n * 3 + 0] = xp0 - x0;
    out_xdiff[(size_t)n * 3 + 1] = xp1 - x1;
    out_xdiff[(size_t)n * 3 + 2] = xp2 - x2;
}

// ---------------- K3: GRU (R5-validated 256-thread low-register version) -----
__global__ __launch_bounds__(256) void gru_kernel(
    const float* __restrict__ h,
    const float* __restrict__ m_sum, const int* __restrict__ cnt,
    const float* __restrict__ W_ih, const float* __restrict__ W_hh,
    const float* __restrict__ b_ih, const float* __restrict__ b_hh,
    float* __restrict__ out_h, int N)
{
    __shared__ float smi[16][68];
    __shared__ float shv[16][68];
    __shared__ float sgi[16][196];
    __shared__ float sgh[16][196];
    int n0 = blockIdx.x * 16;
    int tx = threadIdx.x;
    for (int i = tx; i < 16 * 64; i += 256) {
        int ln = i >> 6, f = i & 63;
        int n = n0 + ln;
        if (n < N) {
            float c = (float)max(cnt[n], 1);
            smi[ln][f] = m_sum[(size_t)n * 64 + f] / c;
            shv[ln][f] = h[(size_t)n * 64 + f];
        } else { smi[ln][f] = 0.0f; shv[ln][f] = 0.0f; }
    }
    __syncthreads();
    {
        int ln = tx >> 4, lane = tx & 15;
        int n = n0 + ln;
        if (n < N) {
            float ai[12], ah[12];
            #pragma unroll
            for (int oq = 0; oq < 12; ++oq) {
                int f = lane * 12 + oq;
                ai[oq] = b_ih[f];
                ah[oq] = b_hh[f];
            }
            #pragma unroll 4
            for (int k4 = 0; k4 < 16; ++k4) {
                float4 mi4 = *(const float4*)&smi[ln][4 * k4];
                float4 hv4 = *(const float4*)&shv[ln][4 * k4];
                #pragma unroll
                for (int oq = 0; oq < 12; ++oq) {
                    int f = lane * 12 + oq;
                    const float* wi = W_ih + (size_t)f * 64 + 4 * k4;
                    const float* wh = W_hh + (size_t)f * 64 + 4 * k4;
                    ai[oq] += mi4.x * wi[0] + mi4.y * wi[1] + mi4.z * wi[2] + mi4.w * wi[3];
                    ah[oq] += hv4.x * wh[0] + hv4.y * wh[1] + hv4.z * wh[2] + hv4.w * wh[3];
                }
            }
            #pragma unroll
            for (int oq = 0; oq < 12; ++oq) {
                int f = lane * 12 + oq;
                sgi[ln][f] = ai[oq];
                sgh[ln][f] = ah[oq];
            }
        }
    }
    __syncthreads();
    {
        int ln = tx >> 4, lane = tx & 15;
        int n = n0 + ln;
        if (n < N) {
            #pragma unroll
            for (int q = 0; q < 4; ++q) {
                int f = lane * 4 + q;
                float r  = sigmoid_f(sgi[ln][f]       + sgh[ln][f]);
                float z  = sigmoid_f(sgi[ln][64 + f]  + sgh[ln][64 + f]);
                float nn = tanhf   (sgi[ln][128 + f] + r * sgh[ln][128 + f]);
                out_h[(size_t)n * 64 + f] = (1.0f - z) * nn + z * shv[ln][f];
            }
        }
    }
}

// ---------------------------------------------------------------------------
extern "C" void kernel_launch(void* const* d_in, const int* in_sizes, int n_in,
                              void* d_out, int out_size, void* d_ws, size_t ws_size,
                              hipStream_t stream)
{
    const float* h    = (const float*)d_in[0];
    const float* x    = (const float*)d_in[1];
    const float* r_ij = (const float*)d_in[2];
    const float* e_ij = (const float*)d_in[3];
    const int*   src  = (const int*)d_in[4];
    const int*   dst  = (const int*)d_in[5];
    const float* W1   = (const float*)d_in[6];
    const float* b1   = (const float*)d_in[7];
    const float* W2   = (const float*)d_in[8];
    const float* b2   = (const float*)d_in[9];
    const float* P1   = (const float*)d_in[10];
    const float* pb1  = (const float*)d_in[11];
    const float* P2   = (const float*)d_in[12];
    const float* pb2  = (const float*)d_in[13];
    const float* W_ih = (const float*)d_in[14];
    const float* W_hh = (const float*)d_in[15];
    const float* b_ih = (const float*)d_in[16];
    const float* b_hh = (const float*)d_in[17];

    int N = in_sizes[0] / 64;
    int E = in_sizes[2];

    float* ws       = (float*)d_ws;
    float* H1a      = ws;                               // N*64 f
    float* H1b      = H1a + (size_t)N * 64;             // N*64 f
    float* m_sum    = H1b + (size_t)N * 64;             // N*64 f
    int*   hist     = (int*)(m_sum + (size_t)N * 64);   // N    i
    int*   cursor   = hist + N;                         // N    i
    int*   order    = cursor + N;                       // E    i
    float* w_sorted = (float*)(order + E);              // E    f
    int*   blksum   = (int*)(w_sorted + E);             // ~64  i

    hipMemsetAsync(m_sum, 0, ((size_t)N * 64 + N) * sizeof(float), stream);

    // ---- stable sort edges by src ----
    hist_kernel<<<2048, 256, 0, stream>>>(src, hist, E);
    int B = (N + SCAN_CHUNK - 1) / SCAN_CHUNK;
    scanA_kernel<<<B, 256, 0, stream>>>(hist, blksum, N);
    scanB_kernel<<<1, 64, 0, stream>>>(blksum, B);
    scanC_kernel<<<B, 256, 0, stream>>>(hist, blksum, cursor, N);
    scatter_kernel<<<2048, 256, 0, stream>>>(src, cursor, order, E);
    sortseg_kernel<<<(N + 255) / 256, 256, 0, stream>>>(cursor, hist, order, N);

    // ---- node precompute (wave-GEMM) ----
    int ntile_n = (N + 15) / 16;
    int grid_n = (ntile_n + 7) / 8;
    node_pre_kernel<<<grid_n, 512, 0, stream>>>(h, W1, b1, H1a, H1b, N);

    // ---- edge pipeline ----
    edge_kernel<<<2048, 256, 0, stream>>>(H1a, H1b, r_ij, src, dst,
        order, W1, W2, b2, P1, pb1, P2, pb2, m_sum, w_sorted, E);

    // ---- outputs ----
    float* out_xmod  = (float*)d_out;
    float* out_xdiff = out_xmod + (size_t)N * 3;
    float* out_h     = out_xdiff + (size_t)N * 3;
    xout_kernel<<<(N + 255) / 256, 256, 0, stream>>>(x, e_ij, order, cursor,
        hist, w_sorted, out_xmod, out_xdiff, N);
    gru_kernel<<<(N + 15) / 16, 256, 0, stream>>>(h, m_sum, hist,
        W_ih, W_hh, b_ih, b_hh, out_h, N);
}

// Round 9
// 3332.218 us; speedup vs baseline: 3.8870x; 1.2762x over previous
//
#include <hip/hip_runtime.h>
#include <cstddef>

// ---------------------------------------------------------------------------
// EGNN layer, fp32. R9 = R8 with:
//   - node_pre reverted to R5-validated 256-thread scalar version (the
//     512-thread wave-GEMM variant cost ~+700us, same spill family as R6 gru)
//   - sortseg: one wave per node, in-register bitonic-64 via shfl_xor
//     (serial fallback for cnt>64). Output identical: ascending edge ids.
//   - gru: explicit float4 weight loads (same FP order).
//   edge / sort-scan / xout identical to R8 (validated, edge @1492us 77% VALU).
// ---------------------------------------------------------------------------

__device__ __forceinline__ float silu_f(float v) {
    float s = 1.0f / (1.0f + expf(-v));
    return v * s;
}
__device__ __forceinline__ float sigmoid_f(float v) { return 1.0f / (1.0f + expf(-v)); }

// ---------------- sort: histogram / scan / scatter / stable fix --------------
__global__ __launch_bounds__(256) void hist_kernel(
    const int* __restrict__ src, int* __restrict__ hist, int E)
{
    int i = blockIdx.x * 256 + threadIdx.x;
    int stride = gridDim.x * 256;
    for (; i < E; i += stride) atomicAdd(&hist[src[i]], 1);
}

#define SCAN_CHUNK 2048

__global__ __launch_bounds__(256) void scanA_kernel(
    const int* __restrict__ hist, int* __restrict__ blksum, int N)
{
    __shared__ int sred[256];
    int b = blockIdx.x, tx = threadIdx.x;
    int base = b * SCAN_CHUNK + tx * 8;
    int s = 0;
    #pragma unroll
    for (int i = 0; i < 8; ++i) { int idx = base + i; if (idx < N) s += hist[idx]; }
    sred[tx] = s; __syncthreads();
    for (int off = 128; off > 0; off >>= 1) {
        if (tx < off) sred[tx] += sred[tx + off];
        __syncthreads();
    }
    if (tx == 0) blksum[b] = sred[0];
}

__global__ void scanB_kernel(int* __restrict__ blksum, int B)
{
    if (blockIdx.x == 0 && threadIdx.x == 0) {
        int acc = 0;
        for (int i = 0; i < B; ++i) { int v = blksum[i]; blksum[i] = acc; acc += v; }
    }
}

__global__ __launch_bounds__(256) void scanC_kernel(
    const int* __restrict__ hist, const int* __restrict__ blksum,
    int* __restrict__ cursor, int N)
{
    __shared__ int sscan[256];
    int b = blockIdx.x, tx = threadIdx.x;
    int base = b * SCAN_CHUNK + tx * 8;
    int s = 0;
    #pragma unroll
    for (int i = 0; i < 8; ++i) { int idx = base + i; if (idx < N) s += hist[idx]; }
    int mysum = s;
    sscan[tx] = s; __syncthreads();
    for (int off = 1; off < 256; off <<= 1) {
        int v = (tx >= off) ? sscan[tx - off] : 0;
        __syncthreads();
        sscan[tx] += v;
        __syncthreads();
    }
    int run = blksum[b] + sscan[tx] - mysum;
    #pragma unroll
    for (int i = 0; i < 8; ++i) {
        int idx = base + i;
        if (idx < N) { cursor[idx] = run; run += hist[idx]; }
    }
}

__global__ __launch_bounds__(256) void scatter_kernel(
    const int* __restrict__ src, int* __restrict__ cursor,
    int* __restrict__ order, int E)
{
    int i = blockIdx.x * 256 + threadIdx.x;
    int stride = gridDim.x * 256;
    for (; i < E; i += stride) {
        int p = atomicAdd(&cursor[src[i]], 1);
        order[p] = i;
    }
}

// stable fix: sort each node's segment ascending. One WAVE per node:
// in-register bitonic-64 via shfl_xor; serial fallback for cnt>64 (rare).
__global__ __launch_bounds__(256) void sortseg_kernel(
    const int* __restrict__ cursor, const int* __restrict__ hist,
    int* __restrict__ order, int N)
{
    int wv = threadIdx.x >> 6;
    int lane = threadIdx.x & 63;
    int n = blockIdx.x * 4 + wv;
    if (n >= N) return;
    int cnt = hist[n];
    if (cnt <= 1) return;
    int st = cursor[n] - cnt;
    if (cnt <= 64) {
        int v = (lane < cnt) ? order[st + lane] : 0x7FFFFFFF;
        #pragma unroll
        for (int k = 2; k <= 64; k <<= 1) {
            #pragma unroll
            for (int j = k >> 1; j > 0; j >>= 1) {
                int partner = __shfl_xor(v, j);
                bool up = ((lane & k) == 0);
                bool keepmin = (((lane & j) == 0) == up);
                v = keepmin ? min(v, partner) : max(v, partner);
            }
        }
        if (lane < cnt) order[st + lane] = v;
    } else if (lane == 0) {
        for (int i = 1; i < cnt; ++i) {
            int v = order[st + i];
            int j = i - 1;
            while (j >= 0 && order[st + j] > v) { order[st + j + 1] = order[st + j]; --j; }
            order[st + j + 1] = v;
        }
    }
}

// ---------------- K1: per-node precompute (R5-validated scalar version) ------
__global__ __launch_bounds__(256) void node_pre_kernel(
    const float* __restrict__ h, const float* __restrict__ W1,
    const float* __restrict__ b1,
    float* __restrict__ H1a, float* __restrict__ H1b, int N)
{
    __shared__ float sh[16][68];
    int n0 = blockIdx.x * 16;
    int tx = threadIdx.x;
    for (int i = tx; i < 16 * 64; i += 256) {
        int ln = i >> 6, k = i & 63;
        int n = n0 + ln;
        sh[ln][k] = (n < N) ? h[(size_t)n * 64 + k] : 0.0f;
    }
    __syncthreads();
    int ln = tx >> 4;
    int lane = tx & 15;
    int n = n0 + ln;
    if (n >= N) return;
    #pragma unroll
    for (int oq = 0; oq < 8; ++oq) {
        int o = lane * 8 + oq;
        const float* wrow = (o < 64) ? (W1 + o * 129) : (W1 + (o - 64) * 129 + 64);
        float acc = (o < 64) ? b1[o] : 0.0f;
        #pragma unroll 8
        for (int k = 0; k < 64; ++k) acc += sh[ln][k] * wrow[k];
        if (o < 64) H1a[(size_t)n * 64 + o] = acc;
        else        H1b[(size_t)n * 64 + (o - 64)] = acc;
    }
}

// ---------------- K2: edge pipeline on sorted order --------------------------
__device__ __forceinline__ void tile_gemm(
    const float (*__restrict__ Ain)[68],   // [k][e]
    const float (*__restrict__ WT)[64],    // [k][f]
    int te, int tf, float (&acc)[4][4])
{
    #pragma unroll
    for (int q = 0; q < 4; ++q)
        acc[q][0] = acc[q][1] = acc[q][2] = acc[q][3] = 0.0f;
    #pragma unroll
    for (int k = 0; k < 64; k += 4) {
        float4 av[4], wv[4];
        #pragma unroll
        for (int kk = 0; kk < 4; ++kk) av[kk] = *(const float4*)&Ain[k + kk][4 * te];
        #pragma unroll
        for (int kk = 0; kk < 4; ++kk) wv[kk] = *(const float4*)&WT[k + kk][4 * tf];
        #pragma unroll
        for (int kk = 0; kk < 4; ++kk) {
            float a0 = av[kk].x, a1 = av[kk].y, a2 = av[kk].z, a3 = av[kk].w;
            float w0 = wv[kk].x, w1 = wv[kk].y, w2 = wv[kk].z, w3 = wv[kk].w;
            acc[0][0] += a0 * w0; acc[0][1] += a0 * w1; acc[0][2] += a0 * w2; acc[0][3] += a0 * w3;
            acc[1][0] += a1 * w0; acc[1][1] += a1 * w1; acc[1][2] += a1 * w2; acc[1][3] += a1 * w3;
            acc[2][0] += a2 * w0; acc[2][1] += a2 * w1; acc[2][2] += a2 * w2; acc[2][3] += a2 * w3;
            acc[3][0] += a3 * w0; acc[3][1] += a3 * w1; acc[3][2] += a3 * w2; acc[3][3] += a3 * w3;
        }
    }
}

__global__ __launch_bounds__(256, 2) void edge_kernel(
    const float* __restrict__ H1a, const float* __restrict__ H1b,
    const float* __restrict__ r_ij,
    const int* __restrict__ src, const int* __restrict__ dst,
    const int* __restrict__ order,
    const float* __restrict__ W1, const float* __restrict__ W2,
    const float* __restrict__ b2, const float* __restrict__ P1,
    const float* __restrict__ pb1, const float* __restrict__ P2,
    const float* __restrict__ pb2,
    float* __restrict__ m_sum, float* __restrict__ w_sorted, int E)
{
    __shared__ float sW2T[64][64];   // [k][f]
    __shared__ float sP1T[64][64];
    __shared__ float sA[64][68];     // [k][e]
    __shared__ float sB[64][68];     // [f][e] (= m) after GEMM1
    __shared__ int   sSrc[64];
    __shared__ int   sRunStart[65];
    __shared__ int   sNRuns, sValid;
    __shared__ float sP2[64], sb2v[64], spb1[64], sW1c[64];
    __shared__ float spb2s;

    int tx = threadIdx.x;
    for (int i = tx; i < 64 * 64; i += 256) {
        int f = i >> 6, k = i & 63;
        sW2T[k][f] = W2[f * 64 + k];
        sP1T[k][f] = P1[f * 64 + k];
    }
    if (tx < 64) {
        sP2[tx]  = P2[tx];
        sb2v[tx] = b2[tx];
        spb1[tx] = pb1[tx];
        sW1c[tx] = W1[tx * 129 + 128];
    }
    if (tx == 0) spb2s = pb2[0];
    __syncthreads();

    int tf = tx & 15, te = tx >> 4;
    int ntile = (E + 63) >> 6;
    for (int t = blockIdx.x; t < ntile; t += gridDim.x) {
        int e0 = t << 6;

        // ---- phase 0: gather via sorted order + first layer -> sA[k][e]
        {
            int le = tx >> 2, j = tx & 3;
            int ep = e0 + le;
            bool ok = ep < E;
            int eid = ok ? order[ep] : 0;
            int s = src[eid], d = dst[eid];
            float r = r_ij[eid];
            if (j == 0) sSrc[le] = ok ? s : -1;
            const float* pa = H1a + (size_t)s * 64 + j * 16;
            const float* pb = H1b + (size_t)d * 64 + j * 16;
            #pragma unroll
            for (int q = 0; q < 4; ++q) {
                float4 va = *(const float4*)(pa + 4 * q);
                float4 vb = *(const float4*)(pb + 4 * q);
                int f = j * 16 + 4 * q;
                sA[f + 0][le] = silu_f(va.x + vb.x + r * sW1c[f + 0]);
                sA[f + 1][le] = silu_f(va.y + vb.y + r * sW1c[f + 1]);
                sA[f + 2][le] = silu_f(va.z + vb.z + r * sW1c[f + 2]);
                sA[f + 3][le] = silu_f(va.w + vb.w + r * sW1c[f + 3]);
            }
        }
        __syncthreads();                        // B1: sA, sSrc ready

        // ---- run detection (wave 0; all ballots with full wave active) ----
        if (tx < 64) {
            int le = tx;
            int sv = sSrc[le];
            bool valid = sv >= 0;
            bool flag = valid && (le == 0 || sSrc[le - 1] != sv);
            unsigned long long vm = __ballot(valid);
            unsigned long long fm = __ballot(flag);
            if (flag) {
                int idx = __popcll(fm & ((1ull << le) - 1ull));
                sRunStart[idx] = le;
            }
            if (le == 0) {
                sNRuns = __popcll(fm);
                sValid = __popcll(vm);
            }
        }

        // ---- GEMM1: m = silu(t1@W2^T + b2) -> sB[f][e]
        {
            float acc[4][4];
            tile_gemm(sA, sW2T, te, tf, acc);
            #pragma unroll
            for (int c = 0; c < 4; ++c) {
                float b = sb2v[4 * tf + c];
                float4 m4;
                m4.x = silu_f(acc[0][c] + b);
                m4.y = silu_f(acc[1][c] + b);
                m4.z = silu_f(acc[2][c] + b);
                m4.w = silu_f(acc[3][c] + b);
                *(float4*)&sB[4 * tf + c][4 * te] = m4;
            }
        }
        __syncthreads();                        // B2: sB, run info ready

        // ---- GEMM2: p = silu(m@P1^T+pb1); w = p.P2 + pb2 -> w_sorted
        {
            float acc[4][4];
            tile_gemm(sB, sP1T, te, tf, acc);
            float w0 = 0.0f, w1 = 0.0f, w2 = 0.0f, w3 = 0.0f;
            #pragma unroll
            for (int c = 0; c < 4; ++c) {
                float p2 = sP2[4 * tf + c];
                float bb = spb1[4 * tf + c];
                w0 += silu_f(acc[0][c] + bb) * p2;
                w1 += silu_f(acc[1][c] + bb) * p2;
                w2 += silu_f(acc[2][c] + bb) * p2;
                w3 += silu_f(acc[3][c] + bb) * p2;
            }
            #pragma unroll
            for (int mask = 1; mask < 16; mask <<= 1) {
                w0 += __shfl_xor(w0, mask);
                w1 += __shfl_xor(w1, mask);
                w2 += __shfl_xor(w2, mask);
                w3 += __shfl_xor(w3, mask);
            }
            if (tf < 4) {
                int eloc = 4 * te + tf;
                int ep = e0 + eloc;
                if (ep < E) {
                    float w = ((tf == 0) ? w0 : (tf == 1) ? w1 : (tf == 2) ? w2 : w3) + spb2s;
                    w_sorted[ep] = w;
                }
            }
        }

        // ---- m segmented reduction, bank-conflict-free layout
        {
            int l15 = tx & 15;
            int eslot = (tx >> 4) & 3;
            int sg = tx >> 6;
            int f = sg * 16 + l15;
            int nr = sNRuns, vc = sValid;
            for (int ridx = 0; ridx < nr; ++ridx) {
                int st = sRunStart[ridx];
                int en = (ridx + 1 < nr) ? sRunStart[ridx + 1] : vc;
                float s = 0.0f;
                for (int e = st + eslot; e < en; e += 4) s += sB[f][e];
                s += __shfl_xor(s, 16);
                s += __shfl_xor(s, 32);
                if (eslot == 0) {
                    int node = sSrc[st];
                    atomicAdd(&m_sum[(size_t)node * 64 + f], s);
                }
            }
        }
        __syncthreads();                        // Bend: before overwriting sA/sSrc
    }
}

// ---------------- K4: x outputs, np-faithful sequential accumulation ---------
__global__ __launch_bounds__(256) void xout_kernel(
    const float* __restrict__ x, const float* __restrict__ e_ij,
    const int* __restrict__ order, const int* __restrict__ cursor,
    const int* __restrict__ hist, const float* __restrict__ w_sorted,
    float* __restrict__ out_xmod, float* __restrict__ out_xdiff, int N)
{
#pragma clang fp contract(off)
    int n = blockIdx.x * 256 + threadIdx.x;
    if (n >= N) return;
    int cnt = hist[n];
    int st = cursor[n] - cnt;
    float x0 = x[(size_t)n * 3 + 0];
    float x1 = x[(size_t)n * 3 + 1];
    float x2 = x[(size_t)n * 3 + 2];
    float s0 = 0.0f, s1 = 0.0f, s2 = 0.0f;
    for (int i = 0; i < cnt; ++i) {
        int eid = order[st + i];
        float w = w_sorted[st + i];
        float t0 = e_ij[(size_t)eid * 3 + 0] * w;
        float t1 = e_ij[(size_t)eid * 3 + 1] * w;
        float t2 = e_ij[(size_t)eid * 3 + 2] * w;
        float r0 = x0 + t0;
        float r1 = x1 + t1;
        float r2 = x2 + t2;
        s0 = s0 + r0;
        s1 = s1 + r1;
        s2 = s2 + r2;
    }
    float c = (float)(cnt > 0 ? cnt : 1);
    float xp0 = s0 / c, xp1 = s1 / c, xp2 = s2 / c;
    out_xmod[(size_t)n * 3 + 0] = xp0 - floorf(xp0);
    out_xmod[(size_t)n * 3 + 1] = xp1 - floorf(xp1);
    out_xmod[(size_t)n * 3 + 2] = xp2 - floorf(xp2);
    out_xdiff[(size_t)n * 3 + 0] = xp0 - x0;
    out_xdiff[(size_t)n * 3 + 1] = xp1 - x1;
    out_xdiff[(size_t)n * 3 + 2] = xp2 - x2;
}

// ---------------- K3: GRU (R5-validated 256-thread low-register version) -----
__global__ __launch_bounds__(256) void gru_kernel(
    const float* __restrict__ h,
    const float* __restrict__ m_sum, const int* __restrict__ cnt,
    const float* __restrict__ W_ih, const float* __restrict__ W_hh,
    const float* __restrict__ b_ih, const float* __restrict__ b_hh,
    float* __restrict__ out_h, int N)
{
    __shared__ float smi[16][68];
    __shared__ float shv[16][68];
    __shared__ float sgi[16][196];
    __shared__ float sgh[16][196];
    int n0 = blockIdx.x * 16;
    int tx = threadIdx.x;
    for (int i = tx; i < 16 * 64; i += 256) {
        int ln = i >> 6, f = i & 63;
        int n = n0 + ln;
        if (n < N) {
            float c = (float)max(cnt[n], 1);
            smi[ln][f] = m_sum[(size_t)n * 64 + f] / c;
            shv[ln][f] = h[(size_t)n * 64 + f];
        } else { smi[ln][f] = 0.0f; shv[ln][f] = 0.0f; }
    }
    __syncthreads();
    {
        int ln = tx >> 4, lane = tx & 15;
        int n = n0 + ln;
        if (n < N) {
            float ai[12], ah[12];
            #pragma unroll
            for (int oq = 0; oq < 12; ++oq) {
                int f = lane * 12 + oq;
                ai[oq] = b_ih[f];
                ah[oq] = b_hh[f];
            }
            #pragma unroll 4
            for (int k4 = 0; k4 < 16; ++k4) {
                float4 mi4 = *(const float4*)&smi[ln][4 * k4];
                float4 hv4 = *(const float4*)&shv[ln][4 * k4];
                #pragma unroll
                for (int oq = 0; oq < 12; ++oq) {
                    int f = lane * 12 + oq;
                    float4 wiv = *(const float4*)(W_ih + (size_t)f * 64 + 4 * k4);
                    float4 whv = *(const float4*)(W_hh + (size_t)f * 64 + 4 * k4);
                    ai[oq] += mi4.x * wiv.x + mi4.y * wiv.y + mi4.z * wiv.z + mi4.w * wiv.w;
                    ah[oq] += hv4.x * whv.x + hv4.y * whv.y + hv4.z * whv.z + hv4.w * whv.w;
                }
            }
            #pragma unroll
            for (int oq = 0; oq < 12; ++oq) {
                int f = lane * 12 + oq;
                sgi[ln][f] = ai[oq];
                sgh[ln][f] = ah[oq];
            }
        }
    }
    __syncthreads();
    {
        int ln = tx >> 4, lane = tx & 15;
        int n = n0 + ln;
        if (n < N) {
            #pragma unroll
            for (int q = 0; q < 4; ++q) {
                int f = lane * 4 + q;
                float r  = sigmoid_f(sgi[ln][f]       + sgh[ln][f]);
                float z  = sigmoid_f(sgi[ln][64 + f]  + sgh[ln][64 + f]);
                float nn = tanhf   (sgi[ln][128 + f] + r * sgh[ln][128 + f]);
                out_h[(size_t)n * 64 + f] = (1.0f - z) * nn + z * shv[ln][f];
            }
        }
    }
}

// ---------------------------------------------------------------------------
extern "C" void kernel_launch(void* const* d_in, const int* in_sizes, int n_in,
                              void* d_out, int out_size, void* d_ws, size_t ws_size,
                              hipStream_t stream)
{
    const float* h    = (const float*)d_in[0];
    const float* x    = (const float*)d_in[1];
    const float* r_ij = (const float*)d_in[2];
    const float* e_ij = (const float*)d_in[3];
    const int*   src  = (const int*)d_in[4];
    const int*   dst  = (const int*)d_in[5];
    const float* W1   = (const float*)d_in[6];
    const float* b1   = (const float*)d_in[7];
    const float* W2   = (const float*)d_in[8];
    const float* b2   = (const float*)d_in[9];
    const float* P1   = (const float*)d_in[10];
    const float* pb1  = (const float*)d_in[11];
    const float* P2   = (const float*)d_in[12];
    const float* pb2  = (const float*)d_in[13];
    const float* W_ih = (const float*)d_in[14];
    const float* W_hh = (const float*)d_in[15];
    const float* b_ih = (const float*)d_in[16];
    const float* b_hh = (const float*)d_in[17];

    int N = in_sizes[0] / 64;
    int E = in_sizes[2];

    float* ws       = (float*)d_ws;
    float* H1a      = ws;                               // N*64 f
    float* H1b      = H1a + (size_t)N * 64;             // N*64 f
    float* m_sum    = H1b + (size_t)N * 64;             // N*64 f
    int*   hist     = (int*)(m_sum + (size_t)N * 64);   // N    i
    int*   cursor   = hist + N;                         // N    i
    int*   order    = cursor + N;                       // E    i
    float* w_sorted = (float*)(order + E);              // E    f
    int*   blksum   = (int*)(w_sorted + E);             // ~64  i

    hipMemsetAsync(m_sum, 0, ((size_t)N * 64 + N) * sizeof(float), stream);

    // ---- stable sort edges by src ----
    hist_kernel<<<2048, 256, 0, stream>>>(src, hist, E);
    int B = (N + SCAN_CHUNK - 1) / SCAN_CHUNK;
    scanA_kernel<<<B, 256, 0, stream>>>(hist, blksum, N);
    scanB_kernel<<<1, 64, 0, stream>>>(blksum, B);
    scanC_kernel<<<B, 256, 0, stream>>>(hist, blksum, cursor, N);
    scatter_kernel<<<2048, 256, 0, stream>>>(src, cursor, order, E);
    sortseg_kernel<<<(N + 3) / 4, 256, 0, stream>>>(cursor, hist, order, N);

    // ---- node precompute ----
    node_pre_kernel<<<(N + 15) / 16, 256, 0, stream>>>(h, W1, b1, H1a, H1b, N);

    // ---- edge pipeline ----
    edge_kernel<<<2048, 256, 0, stream>>>(H1a, H1b, r_ij, src, dst,
        order, W1, W2, b2, P1, pb1, P2, pb2, m_sum, w_sorted, E);

    // ---- outputs ----
    float* out_xmod  = (float*)d_out;
    float* out_xdiff = out_xmod + (size_t)N * 3;
    float* out_h     = out_xdiff + (size_t)N * 3;
    xout_kernel<<<(N + 255) / 256, 256, 0, stream>>>(x, e_ij, order, cursor,
        hist, w_sorted, out_xmod, out_xdiff, N);
    gru_kernel<<<(N + 15) / 16, 256, 0, stream>>>(h, m_sum, hist,
        W_ih, W_hh, b_ih, b_hh, out_h, N);
}